// Round 1
// baseline (5866.080 us; speedup 1.0000x reference)
//
#include <hip/hip_runtime.h>
#include <math.h>

#define GN 32
#define AN 24
#define NN 768
#define EN 6144
#define TN 43008
#define MATD 169
#define EMBD 128
#define RBFD 16
#define SBFW 112
#define HEADS 16
#define CHD 256
#define LN 4
#define NCHK 4
#define ECH (EN/NCHK)      /* 1536 edges per chunk  */
#define TCH (ECH*7)        /* 10752 triplets per chunk */
#define CUTF 5.0f
#define PIF 3.14159265358979323846f
#define INVS 0.25f         /* 1/sqrt(HD=16) */

__device__ __forceinline__ float siluf(float x){
  float s = 1.f/(1.f+expf(-x)); return x*s;
}
__device__ __forceinline__ float silugf(float x){
  float s = 1.f/(1.f+expf(-x)); return s*(1.f + x*(1.f-s));
}

// ---------------- generic 32x32-tile fp32 GEMM ----------------
// TRB=0: C[M,Nc] = A[M,K] @ B[K,Nc]   (B row-major [K,Nc])
// TRB=1: C[M,Nc] = A[M,K] @ B^T       (B row-major [Nc,K])
template<int TRB>
__global__ __launch_bounds__(256)
void gemm32(const float* __restrict__ A, const float* __restrict__ B,
            const float* __restrict__ bias, float* __restrict__ C,
            int M, int Nc, int K, int acc)
{
  __shared__ float As[32][33];
  __shared__ float Bs[32][33];
  const int tx = threadIdx.x, ty = threadIdx.y;
  const int br = blockIdx.y*32, bc = blockIdx.x*32;
  float c00=0.f,c01=0.f,c10=0.f,c11=0.f;
  for (int k0=0;k0<K;k0+=32){
    #pragma unroll
    for (int i=0;i<2;i++){
      int r = br+ty+i*16;
      #pragma unroll
      for (int j=0;j<2;j++){
        int cc = k0+tx+j*16;
        As[ty+i*16][tx+j*16] = (r<M && cc<K) ? A[(size_t)r*K+cc] : 0.f;
      }
    }
    #pragma unroll
    for (int i=0;i<2;i++){
      int kk = k0+ty+i*16;
      #pragma unroll
      for (int j=0;j<2;j++){
        int cc = bc+tx+j*16;
        float v = 0.f;
        if (kk<K && cc<Nc) v = (TRB==0) ? B[(size_t)kk*Nc+cc] : B[(size_t)cc*K+kk];
        Bs[ty+i*16][tx+j*16] = v;
      }
    }
    __syncthreads();
    #pragma unroll
    for (int kk=0;kk<32;kk++){
      float a0=As[ty][kk], a1=As[ty+16][kk];
      float b0=Bs[kk][tx], b1=Bs[kk][tx+16];
      c00+=a0*b0; c01+=a0*b1; c10+=a1*b0; c11+=a1*b1;
    }
    __syncthreads();
  }
  int r0=br+ty, r1=br+ty+16, cc0=bc+tx, cc1=bc+tx+16;
  float b0v = (bias && cc0<Nc)? bias[cc0]:0.f;
  float b1v = (bias && cc1<Nc)? bias[cc1]:0.f;
  if (r0<M){
    if (cc0<Nc){ size_t o=(size_t)r0*Nc+cc0; C[o]=(acc?C[o]:0.f)+c00+b0v; }
    if (cc1<Nc){ size_t o=(size_t)r0*Nc+cc1; C[o]=(acc?C[o]:0.f)+c01+b1v; }
  }
  if (r1<M){
    if (cc0<Nc){ size_t o=(size_t)r1*Nc+cc0; C[o]=(acc?C[o]:0.f)+c10+b0v; }
    if (cc1<Nc){ size_t o=(size_t)r1*Nc+cc1; C[o]=(acc?C[o]:0.f)+c11+b1v; }
  }
}

// ---------------- forward geometry / elementwise ----------------
__global__ void k_edge_geom(const float* __restrict__ pos, const int* __restrict__ ei,
                            float* __restrict__ dv, float* __restrict__ env,
                            float* __restrict__ denv, float* __restrict__ nrbf)
{
  int e = blockIdx.x*256+threadIdx.x; if(e>=EN) return;
  int s = ei[e], t = ei[EN+e];
  float dx=pos[3*s]-pos[3*t], dy=pos[3*s+1]-pos[3*t+1], dz=pos[3*s+2]-pos[3*t+2];
  float d = sqrtf(dx*dx+dy*dy+dz*dz);
  float u = d/CUTF, ev=0.f, dev=0.f;
  if (u<1.f){
    float u2=u*u, u4=u2*u2, u5=u4*u;
    ev  = 1.f - 21.f*u5 + 35.f*u5*u - 15.f*u5*u2;
    dev = (-105.f*u4 + 210.f*u5 - 105.f*u4*u2)/CUTF;
  }
  dv[e]=d; env[e]=ev; denv[e]=dev;
  const float C0 = sqrtf(2.f/CUTF);
  #pragma unroll
  for (int n=0;n<RBFD;n++){
    float wv = (n+1)*PIF/CUTF;
    nrbf[e*RBFD+n] = C0*sinf(wv*d)/d*ev;
  }
}

__global__ void k_scale_ea(const float* __restrict__ ea, const float* __restrict__ env,
                           float* __restrict__ ob)
{
  int i = blockIdx.x*256+threadIdx.x; if(i>=EN*MATD) return;
  ob[i] = ea[i]*env[i/MATD];
}

__global__ void k_ang(const float* __restrict__ pos, const int* __restrict__ ai,
                      const int* __restrict__ aj, const int* __restrict__ ak,
                      float* __restrict__ ang)
{
  int t = blockIdx.x*256+threadIdx.x; if(t>=TN) return;
  int i=ai[t], j=aj[t], k=ak[t];
  float jix=pos[3*i]-pos[3*j], jiy=pos[3*i+1]-pos[3*j+1], jiz=pos[3*i+2]-pos[3*j+2];
  float jkx=pos[3*k]-pos[3*j], jky=pos[3*k+1]-pos[3*j+1], jkz=pos[3*k+2]-pos[3*j+2];
  float cx=jiy*jkz-jiz*jky, cy=jiz*jkx-jix*jkz, cz=jix*jky-jiy*jkx;
  float cn=sqrtf(cx*cx+cy*cy+cz*cz);
  float dt=jix*jkx+jiy*jky+jiz*jkz;
  ang[t]=atan2f(cn,dt);
}

__global__ void k_sbf(const float* __restrict__ ang, const float* __restrict__ nrbf,
                      const int* __restrict__ neo0, float* __restrict__ sbf)
{
  int i = blockIdx.x*256+threadIdx.x; if(i>=TN*SBFW) return;
  int t = i/SBFW, col = i - t*SBFW;
  int l = col>>4, n = col&15;
  int e2 = neo0[t];
  sbf[i] = cosf((float)l*ang[t])*nrbf[e2*RBFD+n];
}

__global__ void k_embx(const int* __restrict__ x, const float* __restrict__ tab,
                       float* __restrict__ embx)
{
  int i = blockIdx.x*256+threadIdx.x; if(i>=NN*EMBD) return;
  int n=i>>7, c=i&127;
  embx[i]=tab[x[n]*EMBD+c];
}

__global__ void k_cat(const float* __restrict__ p1, const float* __restrict__ p2,
                      float* __restrict__ cat)
{
  int i=blockIdx.x*256+threadIdx.x; if(i>=EN*CHD) return;
  int e=i>>8, j=i&255;
  cat[i] = (j<128)? siluf(p1[e*128+j]) : siluf(p2[e*128+j-128]);
}

__global__ void k_silu(const float* __restrict__ in, float* __restrict__ ob, int n)
{
  int i=blockIdx.x*256+threadIdx.x; if(i>=n) return;
  ob[i]=siluf(in[i]);
}

__global__ void k_residual(const float* __restrict__ hin, const float* __restrict__ opre,
                           float* __restrict__ hout)
{
  int i=blockIdx.x*256+threadIdx.x; if(i>=EN*CHD) return;
  hout[i]=hin[i]+siluf(opre[i]);
}

// ---------------- attention (per dst-edge x head; 7 contiguous triplets) ----------------
__global__ void k_attn_fwd(const float* __restrict__ q, const float* __restrict__ kb,
                           const float* __restrict__ vb, const float* __restrict__ esb,
                           const float* __restrict__ eatn, const int* __restrict__ neo0,
                           float* __restrict__ attn, float* __restrict__ agg, int e0)
{
  int idx = blockIdx.x*256+threadIdx.x;
  if (idx>=ECH*HEADS) return;
  int e = e0 + idx/HEADS, h = idx%HEADS;
  int n = e>>3, t0 = e0*7;
  float qv[16], evv[16];
  #pragma unroll
  for (int d=0;d<16;d++){ qv[d]=q[e*CHD+h*16+d]; evv[d]=eatn[n*CHD+h*16+d]; }
  float lg[7]; int src[7];
  for (int jj=0;jj<7;jj++){
    int t=e*7+jj; int sE=neo0[t]; src[jj]=sE;
    const float* ep = esb + (size_t)(t-t0)*CHD + h*16;
    const float* kp = kb + (size_t)sE*CHD + h*16;
    float s=0.f;
    #pragma unroll
    for (int d=0;d<16;d++) s += qv[d]*(kp[d]*ep[d]+evv[d]);
    lg[jj]=s*INVS;
  }
  float m=lg[0];
  for(int jj=1;jj<7;jj++) m=fmaxf(m,lg[jj]);
  float ex[7], den=0.f;
  for(int jj=0;jj<7;jj++){ ex[jj]=expf(lg[jj]-m); den+=ex[jj]; }
  float rd=1.f/(den+1e-16f);
  float av[16];
  #pragma unroll
  for(int d=0;d<16;d++) av[d]=0.f;
  for(int jj=0;jj<7;jj++){
    int t=e*7+jj;
    float at=ex[jj]*rd;
    attn[(size_t)t*HEADS+h]=at;
    const float* ep = esb + (size_t)(t-t0)*CHD + h*16;
    const float* vp = vb + (size_t)src[jj]*CHD + h*16;
    #pragma unroll
    for(int d=0;d<16;d++) av[d]+=at*vp[d]*ep[d];
  }
  #pragma unroll
  for(int d=0;d<16;d++) agg[e*CHD+h*16+d]=av[d];
}

__global__ void k_edge_out(const float* __restrict__ g1pre, const float* __restrict__ w2,
                           const float* __restrict__ b2, const int* __restrict__ eb,
                           float* __restrict__ ob)
{
  int e=blockIdx.x*256+threadIdx.x; if(e>=EN) return;
  float s=b2[0];
  for(int c=0;c<EMBD;c++) s += siluf(g1pre[e*EMBD+c])*w2[c];
  atomicAdd(&ob[eb[e]], s);
}

// ---------------- backward ----------------
__global__ void k_gg1(const float* __restrict__ g1pre, const float* __restrict__ w2,
                      float* __restrict__ gg1)
{
  int i=blockIdx.x*256+threadIdx.x; if(i>=EN*EMBD) return;
  gg1[i]=w2[i&127]*silugf(g1pre[i]);
}

__global__ void k_gopre(const float* __restrict__ gh, const float* __restrict__ opre,
                        float* __restrict__ ob)
{
  int i=blockIdx.x*256+threadIdx.x; if(i>=EN*CHD) return;
  ob[i]=gh[i]*silugf(opre[i]);
}

__global__ void k_attn_bwd_edge(const float* __restrict__ q, const float* __restrict__ kb,
                                const float* __restrict__ vb, const float* __restrict__ esb,
                                const float* __restrict__ eatn, const float* __restrict__ attn,
                                const float* __restrict__ gagg, const int* __restrict__ neo0,
                                float* __restrict__ gq, float* __restrict__ gesb,
                                float* __restrict__ glog, int e0)
{
  int idx=blockIdx.x*256+threadIdx.x;
  if(idx>=ECH*HEADS) return;
  int e=e0+idx/HEADS, h=idx%HEADS;
  int n=e>>3, t0=e0*7;
  float qv[16], evv[16], gv[16];
  #pragma unroll
  for(int d=0;d<16;d++){
    qv[d]=q[e*CHD+h*16+d];
    evv[d]=eatn[n*CHD+h*16+d];
    gv[d]=gagg[e*CHD+h*16+d];
  }
  float ga[7], at[7]; int src[7];
  for(int jj=0;jj<7;jj++){
    int t=e*7+jj; int sE=neo0[t]; src[jj]=sE;
    at[jj]=attn[(size_t)t*HEADS+h];
    const float* ep=esb+(size_t)(t-t0)*CHD+h*16;
    const float* vp=vb+(size_t)sE*CHD+h*16;
    float s=0.f;
    #pragma unroll
    for(int d=0;d<16;d++) s+=gv[d]*vp[d]*ep[d];
    ga[jj]=s;
  }
  float sm=0.f;
  for(int jj=0;jj<7;jj++) sm+=at[jj]*ga[jj];
  float gqv[16];
  #pragma unroll
  for(int d=0;d<16;d++) gqv[d]=0.f;
  for(int jj=0;jj<7;jj++){
    int t=e*7+jj; int sE=src[jj];
    float gl=at[jj]*(ga[jj]-sm);
    glog[(size_t)t*HEADS+h]=gl;
    const float* ep=esb+(size_t)(t-t0)*CHD+h*16;
    const float* kp=kb+(size_t)sE*CHD+h*16;
    const float* vp=vb+(size_t)sE*CHD+h*16;
    float* gp=gesb+(size_t)(t-t0)*CHD+h*16;
    #pragma unroll
    for(int d=0;d<16;d++){
      float es=ep[d], kk=kp[d];
      gqv[d]+=gl*INVS*(kk*es+evv[d]);
      gp[d]=at[jj]*vp[d]*gv[d]+gl*INVS*qv[d]*kk;
    }
  }
  #pragma unroll
  for(int d=0;d<16;d++) gq[e*CHD+h*16+d]=gqv[d];
}

// gather per src edge: its 7 triplets are t = n*56 + a*7 + (b - (b>a)), a != b
__global__ void k_attn_bwd_src(const float* __restrict__ q, const float* __restrict__ esb,
                               const float* __restrict__ attn, const float* __restrict__ gagg,
                               const float* __restrict__ glog,
                               float* __restrict__ gk, float* __restrict__ gv, int e0)
{
  int idx=blockIdx.x*256+threadIdx.x;
  if(idx>=ECH*HEADS) return;
  int e=e0+idx/HEADS, h=idx%HEADS;   // e = src edge
  int n=e>>3, b=e&7, t0=e0*7;
  float gkk[16], gvv[16];
  #pragma unroll
  for(int d=0;d<16;d++){ gkk[d]=0.f; gvv[d]=0.f; }
  for(int a=0;a<8;a++){
    if(a==b) continue;
    int t = n*56 + a*7 + (b>a ? b-1 : b);
    int de = n*8 + a;
    float gl=glog[(size_t)t*HEADS+h]*INVS;
    float at=attn[(size_t)t*HEADS+h];
    const float* ep=esb+(size_t)(t-t0)*CHD+h*16;
    const float* qp=q+(size_t)de*CHD+h*16;
    const float* gp=gagg+(size_t)de*CHD+h*16;
    #pragma unroll
    for(int d=0;d<16;d++){
      float es=ep[d];
      gkk[d]+=gl*qp[d]*es;
      gvv[d]+=at*es*gp[d];
    }
  }
  #pragma unroll
  for(int d=0;d<16;d++){ gk[e*CHD+h*16+d]=gkk[d]; gv[e*CHD+h*16+d]=gvv[d]; }
}

__global__ void k_gp3(float* __restrict__ gh, const float* __restrict__ p3)
{
  int i=blockIdx.x*256+threadIdx.x; if(i>=EN*EMBD) return;
  gh[i]*=silugf(p3[i]);
}

__global__ void k_split(const float* __restrict__ gcat, const float* __restrict__ p1,
                        const float* __restrict__ p2, float* __restrict__ gp1,
                        float* __restrict__ gp2)
{
  int i=blockIdx.x*256+threadIdx.x; if(i>=EN*EMBD) return;
  int e=i>>7, c=i&127;
  gp1[i]=gcat[e*CHD+c]*silugf(p1[i]);
  gp2[i]=gcat[e*CHD+128+c]*silugf(p2[i]);
}

__global__ void k_edge_bwd(const float* __restrict__ geaenv, const float* __restrict__ ea,
                           const float* __restrict__ env, const float* __restrict__ denv,
                           const float* __restrict__ dv, const float* __restrict__ gnr,
                           float* __restrict__ eag, float* __restrict__ gd)
{
  int e=blockIdx.x*256+threadIdx.x; if(e>=EN) return;
  float ev=env[e], dev=denv[e], d=dv[e];
  float gmat=0.f;
  for(int m=0;m<MATD;m++){
    float g=geaenv[e*MATD+m];
    eag[e*MATD+m]=g*ev;
    gmat+=g*ea[e*MATD+m];
  }
  float acc=gmat*dev;
  const float C0=sqrtf(2.f/CUTF);
  for(int n=0;n<RBFD;n++){
    float wv=(n+1)*PIF/CUTF;
    float sn,cs; sincosf(wv*d,&sn,&cs);
    float rb=C0*sn/d;
    float rbp=C0*(wv*cs/d - sn/(d*d));
    acc += gnr[e*RBFD+n]*(rbp*ev+rb*dev);
  }
  gd[e]=acc;
}

__global__ void k_sbf_bwd(const float* __restrict__ gsbf, const float* __restrict__ ang,
                          const float* __restrict__ dv, const float* __restrict__ env,
                          const float* __restrict__ denv, const float* __restrict__ nrbf,
                          const int* __restrict__ neo0, const int* __restrict__ ai,
                          const int* __restrict__ aj, const int* __restrict__ ak,
                          const float* __restrict__ pos,
                          float* __restrict__ gd, float* __restrict__ gpos)
{
  int t=blockIdx.x*256+threadIdx.x; if(t>=TN) return;
  int e2=neo0[t];
  float a=ang[t];
  float rad[16], gr[16];
  #pragma unroll
  for(int n=0;n<16;n++){ rad[n]=nrbf[e2*RBFD+n]; gr[n]=0.f; }
  float gang=0.f;
  for(int l=0;l<7;l++){
    float sl,cl; sincosf((float)l*a,&sl,&cl);
    float srow=0.f;
    #pragma unroll
    for(int n=0;n<16;n++){
      float gs=gsbf[(size_t)t*SBFW+l*16+n];
      gr[n]+=gs*cl;
      srow+=gs*rad[n];
    }
    gang+=-(float)l*sl*srow;
  }
  float d2=dv[e2], ev=env[e2], dev=denv[e2];
  const float C0=sqrtf(2.f/CUTF);
  float gdd=0.f;
  for(int n=0;n<16;n++){
    float wv=(n+1)*PIF/CUTF;
    float sn,cs; sincosf(wv*d2,&sn,&cs);
    float rb=C0*sn/d2;
    float rbp=C0*(wv*cs/d2 - sn/(d2*d2));
    gdd+=gr[n]*(rbp*ev+rb*dev);
  }
  atomicAdd(&gd[e2],gdd);
  // angle -> positions
  int i=ai[t], j=aj[t], k=ak[t];
  float jix=pos[3*i]-pos[3*j], jiy=pos[3*i+1]-pos[3*j+1], jiz=pos[3*i+2]-pos[3*j+2];
  float jkx=pos[3*k]-pos[3*j], jky=pos[3*k+1]-pos[3*j+1], jkz=pos[3*k+2]-pos[3*j+2];
  float cx=jiy*jkz-jiz*jky, cy=jiz*jkx-jix*jkz, cz=jix*jky-jiy*jkx;
  float cn2=cx*cx+cy*cy+cz*cz;
  float cn=sqrtf(cn2);
  float dt=jix*jkx+jiy*jky+jiz*jkz;
  float den=cn2+dt*dt;
  float coef=gang/den;
  float rc=dt/cn;
  float axv=jky*cz-jkz*cy, ayv=jkz*cx-jkx*cz, azv=jkx*cy-jky*cx;  // jk x c
  float bxv=cy*jiz-cz*jiy, byv=cz*jix-cx*jiz, bzv=cx*jiy-cy*jix;  // c x ji
  float gjix=coef*(rc*axv-cn*jkx), gjiy=coef*(rc*ayv-cn*jky), gjiz=coef*(rc*azv-cn*jkz);
  float gjkx=coef*(rc*bxv-cn*jix), gjky=coef*(rc*byv-cn*jiy), gjkz=coef*(rc*bzv-cn*jiz);
  atomicAdd(&gpos[3*i],gjix); atomicAdd(&gpos[3*i+1],gjiy); atomicAdd(&gpos[3*i+2],gjiz);
  atomicAdd(&gpos[3*k],gjkx); atomicAdd(&gpos[3*k+1],gjky); atomicAdd(&gpos[3*k+2],gjkz);
  atomicAdd(&gpos[3*j],-(gjix+gjkx)); atomicAdd(&gpos[3*j+1],-(gjiy+gjky)); atomicAdd(&gpos[3*j+2],-(gjiz+gjkz));
}

__global__ void k_d_bwd(const float* __restrict__ gd, const float* __restrict__ dv,
                        const float* __restrict__ pos, const int* __restrict__ ei,
                        float* __restrict__ gpos)
{
  int e=blockIdx.x*256+threadIdx.x; if(e>=EN) return;
  int s=ei[e], t=ei[EN+e];
  float g=gd[e]/dv[e];
  float dx=pos[3*s]-pos[3*t], dy=pos[3*s+1]-pos[3*t+1], dz=pos[3*s+2]-pos[3*t+2];
  atomicAdd(&gpos[3*s], g*dx); atomicAdd(&gpos[3*s+1], g*dy); atomicAdd(&gpos[3*s+2], g*dz);
  atomicAdd(&gpos[3*t], -g*dx); atomicAdd(&gpos[3*t+1], -g*dy); atomicAdd(&gpos[3*t+2], -g*dz);
}

// contrib[e,a,c] = sum_m edge_attr_grad[e,a,c,m] * e_a_g[e,m]; accumulated per (graph*A+a, c)
__global__ void k_einsum(const float* __restrict__ G_, const float* __restrict__ eag,
                         const int* __restrict__ eb, float* __restrict__ gpos)
{
  int item = blockIdx.x*4 + (threadIdx.x>>6);
  int lane = threadIdx.x&63;
  if(item>=EN*AN*3) return;
  int e = item/(AN*3);
  int rem = item - e*(AN*3);
  size_t base=(size_t)item*MATD;
  const float* ep = eag + (size_t)e*MATD;
  float s=0.f;
  for(int m=lane;m<MATD;m+=64) s+=G_[base+m]*ep[m];
  for(int o=32;o>0;o>>=1) s+=__shfl_down(s,o,64);
  if(lane==0) atomicAdd(&gpos[eb[e]*(AN*3)+rem], s);
}

__global__ void k_force(const float* __restrict__ gpos, float* __restrict__ ob)
{
  int i=blockIdx.x*256+threadIdx.x; if(i>=NN*3) return;
  ob[GN+i]=-gpos[i];
}

extern "C" void kernel_launch(void* const* d_in, const int* in_sizes, int n_in,
                              void* d_out, int out_size, void* d_ws, size_t ws_size,
                              hipStream_t stream)
{
  const int*   x      = (const int*)d_in[0];
  const int*   ei     = (const int*)d_in[1];
  const int*   neo    = (const int*)d_in[2];
  const int*   ai     = (const int*)d_in[3];
  const int*   aj     = (const int*)d_in[4];
  const int*   ak     = (const int*)d_in[5];
  const int*   eb     = (const int*)d_in[6];
  const float* pos    = (const float*)d_in[8];
  const float* eattr  = (const float*)d_in[9];
  const float* eagrad = (const float*)d_in[10];
  const float* etab   = (const float*)d_in[11];
  const float* matW   = (const float*)d_in[12];
  const float* matB   = (const float*)d_in[13];
  const float* rbfW   = (const float*)d_in[14];
  const float* rbfB   = (const float*)d_in[15];
  const float* embtW  = (const float*)d_in[16];
  const float* embtB  = (const float*)d_in[17];
  const float* inW    = (const float*)d_in[18];
  const float* inB    = (const float*)d_in[19];
  const float* Wq     = (const float*)d_in[20];
  const float* Wk     = (const float*)d_in[21];
  const float* Wv     = (const float*)d_in[22];
  const float* Wo     = (const float*)d_in[23];
  const float* bo     = (const float*)d_in[24];
  const float* Wsbf   = (const float*)d_in[25];
  const float* Weat   = (const float*)d_in[26];
  const float* o1W    = (const float*)d_in[27];
  const float* o1B    = (const float*)d_in[28];
  const float* o2W    = (const float*)d_in[29];
  const float* o2B    = (const float*)d_in[30];
  float* out = (float*)d_out;
  (void)in_sizes; (void)n_in; (void)out_size; (void)ws_size;

  float* w=(float*)d_ws;
  size_t off=0;
  auto A=[&](size_t n){ float* p=w+off; off+=n; return p; };
  float* dv    = A(EN);
  float* env   = A(EN);
  float* denv  = A(EN);
  float* gd    = A(EN);
  float* nrbf  = A((size_t)EN*RBFD);
  float* gnr   = A((size_t)EN*RBFD);
  float* easc  = A((size_t)EN*MATD);
  float* geaenv= A((size_t)EN*MATD);
  float* eag   = A((size_t)EN*MATD);
  float* p1    = A((size_t)EN*EMBD);
  float* p2    = A((size_t)EN*EMBD);
  float* p3    = A((size_t)EN*EMBD);
  float* hpre  = A((size_t)EN*EMBD);
  float* g1pre = A((size_t)EN*EMBD);
  float* gg1   = A((size_t)EN*EMBD);   // later reused as grad_p1
  float* ghpre = A((size_t)EN*EMBD);
  float* gp2   = A((size_t)EN*EMBD);
  float* hlay  = A((size_t)5*EN*CHD);
  float* cat   = A((size_t)EN*CHD);
  float* qb    = A((size_t)EN*CHD);
  float* kb    = A((size_t)EN*CHD);
  float* vb    = A((size_t)EN*CHD);
  float* gq    = A((size_t)EN*CHD);
  float* gk    = A((size_t)EN*CHD);
  float* gv    = A((size_t)EN*CHD);
  float* sc1   = A((size_t)EN*CHD);    // gopre
  float* sc2   = A((size_t)EN*CHD);    // agg fwd / grad_agg bwd / grad_cat tail
  float* gradh = A((size_t)EN*CHD);
  float* opre  = A((size_t)4*EN*CHD);
  float* sbf   = A((size_t)TN*SBFW);
  float* gsbf  = A((size_t)TN*SBFW);
  float* angb  = A(TN);
  float* attn  = A((size_t)4*TN*HEADS);
  float* glog  = A((size_t)TN*HEADS);
  float* esbb  = A((size_t)TCH*CHD);
  float* gesbb = A((size_t)TCH*CHD);
  float* eatn  = A((size_t)NN*CHD);
  float* embx  = A((size_t)NN*EMBD);
  float* gpos  = A((size_t)NN*3);
  // total ~58.4M floats ~= 234 MB

  hipMemsetAsync(out, 0, GN*sizeof(float), stream);
  hipMemsetAsync(gsbf, 0, (size_t)TN*SBFW*sizeof(float), stream);
  hipMemsetAsync(gpos, 0, (size_t)NN*3*sizeof(float), stream);

  auto gemm_nn=[&](const float*Ag,const float*Bg,const float*bias,float*Cg,int M,int Nc,int K,int acc){
    hipLaunchKernelGGL((gemm32<0>), dim3((Nc+31)/32,(M+31)/32), dim3(16,16),0,stream, Ag,Bg,bias,Cg,M,Nc,K,acc);
  };
  auto gemm_nt=[&](const float*Ag,const float*Bg,const float*bias,float*Cg,int M,int Nc,int K,int acc){
    hipLaunchKernelGGL((gemm32<1>), dim3((Nc+31)/32,(M+31)/32), dim3(16,16),0,stream, Ag,Bg,bias,Cg,M,Nc,K,acc);
  };

  // ---------- forward ----------
  hipLaunchKernelGGL(k_edge_geom, dim3((EN+255)/256),dim3(256),0,stream, pos,ei,dv,env,denv,nrbf);
  hipLaunchKernelGGL(k_scale_ea, dim3((EN*MATD+255)/256),dim3(256),0,stream, eattr,env,easc);
  hipLaunchKernelGGL(k_ang, dim3((TN+255)/256),dim3(256),0,stream, pos,ai,aj,ak,angb);
  hipLaunchKernelGGL(k_sbf, dim3((TN*SBFW+255)/256),dim3(256),0,stream, angb,nrbf,neo,sbf);
  hipLaunchKernelGGL(k_embx, dim3((NN*EMBD+255)/256),dim3(256),0,stream, x,etab,embx);

  gemm_nn(easc, matW, matB, p1, EN, EMBD, MATD, 0);
  gemm_nn(nrbf, rbfW, rbfB, p2, EN, EMBD, RBFD, 0);
  hipLaunchKernelGGL(k_cat, dim3((EN*CHD+255)/256),dim3(256),0,stream, p1,p2,cat);
  gemm_nn(cat, embtW, embtB, p3, EN, EMBD, CHD, 0);
  hipLaunchKernelGGL(k_silu, dim3((EN*EMBD+255)/256),dim3(256),0,stream, p3,hpre,EN*EMBD);
  gemm_nn(hpre, inW, inB, hlay, EN, CHD, EMBD, 0);

  for (int l=0;l<LN;l++){
    const float* hl=hlay+(size_t)l*EN*CHD;
    gemm_nn(hl, Wq+(size_t)l*CHD*CHD, nullptr, qb, EN, CHD, CHD, 0);
    gemm_nn(hl, Wk+(size_t)l*CHD*CHD, nullptr, kb, EN, CHD, CHD, 0);
    gemm_nn(hl, Wv+(size_t)l*CHD*CHD, nullptr, vb, EN, CHD, CHD, 0);
    gemm_nn(embx, Weat+(size_t)l*EMBD*CHD, nullptr, eatn, NN, CHD, EMBD, 0);
    float* attl = attn+(size_t)l*TN*HEADS;
    for (int c=0;c<NCHK;c++){
      int e0=c*ECH, t0=e0*7;
      gemm_nn(sbf+(size_t)t0*SBFW, Wsbf+(size_t)l*SBFW*CHD, nullptr, esbb, TCH, CHD, SBFW, 0);
      hipLaunchKernelGGL(k_attn_fwd, dim3((ECH*HEADS+255)/256),dim3(256),0,stream,
                         qb,kb,vb,esbb,eatn,neo,attl,sc2,e0);
    }
    float* opl=opre+(size_t)l*EN*CHD;
    gemm_nn(sc2, Wo+(size_t)l*CHD*CHD, bo+(size_t)l*CHD, opl, EN, CHD, CHD, 0);
    hipLaunchKernelGGL(k_residual, dim3((EN*CHD+255)/256),dim3(256),0,stream,
                       hl,opl,hlay+(size_t)(l+1)*EN*CHD);
  }
  const float* h4=hlay+(size_t)4*EN*CHD;
  gemm_nn(h4, o1W, o1B, g1pre, EN, EMBD, CHD, 0);
  hipLaunchKernelGGL(k_edge_out, dim3((EN+255)/256),dim3(256),0,stream, g1pre,o2W,o2B,eb,out);

  // ---------- backward ----------
  hipLaunchKernelGGL(k_gg1, dim3((EN*EMBD+255)/256),dim3(256),0,stream, g1pre,o2W,gg1);
  gemm_nt(gg1, o1W, nullptr, gradh, EN, CHD, EMBD, 0);

  for (int l=LN-1;l>=0;l--){
    const float* hl=hlay+(size_t)l*EN*CHD;
    float* opl=opre+(size_t)l*EN*CHD;
    float* attl=attn+(size_t)l*TN*HEADS;
    hipLaunchKernelGGL(k_gopre, dim3((EN*CHD+255)/256),dim3(256),0,stream, gradh,opl,sc1);
    gemm_nt(sc1, Wo+(size_t)l*CHD*CHD, nullptr, sc2, EN, CHD, CHD, 0);   // grad_agg
    gemm_nn(hl, Wq+(size_t)l*CHD*CHD, nullptr, qb, EN, CHD, CHD, 0);
    gemm_nn(hl, Wk+(size_t)l*CHD*CHD, nullptr, kb, EN, CHD, CHD, 0);
    gemm_nn(hl, Wv+(size_t)l*CHD*CHD, nullptr, vb, EN, CHD, CHD, 0);
    gemm_nn(embx, Weat+(size_t)l*EMBD*CHD, nullptr, eatn, NN, CHD, EMBD, 0);
    for (int c=0;c<NCHK;c++){
      int e0=c*ECH, t0=e0*7;
      gemm_nn(sbf+(size_t)t0*SBFW, Wsbf+(size_t)l*SBFW*CHD, nullptr, esbb, TCH, CHD, SBFW, 0);
      hipLaunchKernelGGL(k_attn_bwd_edge, dim3((ECH*HEADS+255)/256),dim3(256),0,stream,
                         qb,kb,vb,esbb,eatn,attl,sc2,neo,gq,gesbb,glog,e0);
      hipLaunchKernelGGL(k_attn_bwd_src, dim3((ECH*HEADS+255)/256),dim3(256),0,stream,
                         qb,esbb,attl,sc2,glog,gk,gv,e0);
      gemm_nt(gesbb, Wsbf+(size_t)l*SBFW*CHD, nullptr, gsbf+(size_t)t0*SBFW, TCH, SBFW, CHD, 1);
    }
    gemm_nt(gq, Wq+(size_t)l*CHD*CHD, nullptr, gradh, EN, CHD, CHD, 1);
    gemm_nt(gk, Wk+(size_t)l*CHD*CHD, nullptr, gradh, EN, CHD, CHD, 1);
    gemm_nt(gv, Wv+(size_t)l*CHD*CHD, nullptr, gradh, EN, CHD, CHD, 1);
  }

  gemm_nt(gradh, inW, nullptr, ghpre, EN, EMBD, CHD, 0);
  hipLaunchKernelGGL(k_gp3, dim3((EN*EMBD+255)/256),dim3(256),0,stream, ghpre,p3);
  gemm_nt(ghpre, embtW, nullptr, sc2, EN, CHD, EMBD, 0);  // grad_cat
  hipLaunchKernelGGL(k_split, dim3((EN*EMBD+255)/256),dim3(256),0,stream, sc2,p1,p2,gg1,gp2);
  gemm_nt(gp2, rbfW, nullptr, gnr, EN, RBFD, EMBD, 0);
  gemm_nt(gg1, matW, nullptr, geaenv, EN, MATD, EMBD, 0);
  hipLaunchKernelGGL(k_edge_bwd, dim3((EN+255)/256),dim3(256),0,stream,
                     geaenv,eattr,env,denv,dv,gnr,eag,gd);
  hipLaunchKernelGGL(k_sbf_bwd, dim3((TN+255)/256),dim3(256),0,stream,
                     gsbf,angb,dv,env,denv,nrbf,neo,ai,aj,ak,pos,gd,gpos);
  hipLaunchKernelGGL(k_d_bwd, dim3((EN+255)/256),dim3(256),0,stream, gd,dv,pos,ei,gpos);
  hipLaunchKernelGGL(k_einsum, dim3((EN*AN*3+3)/4),dim3(256),0,stream, eagrad,eag,eb,gpos);
  hipLaunchKernelGGL(k_force, dim3((NN*3+255)/256),dim3(256),0,stream, gpos,out);
}

// Round 2
// 5859.524 us; speedup vs baseline: 1.0011x; 1.0011x over previous
//
#include <hip/hip_runtime.h>
#include <math.h>

#define GN 32
#define AN 24
#define NN 768
#define EN 6144
#define TN 43008
#define MATD 169
#define EMBD 128
#define RBFD 16
#define SBFW 112
#define HEADS 16
#define CHD 256
#define LN 4
#define NCHK 4
#define ECH (EN/NCHK)      /* 1536 edges per chunk  */
#define TCH (ECH*7)        /* 10752 triplets per chunk */
#define CUTF 5.0f
#define PIF 3.14159265358979323846f
#define INVS 0.25f         /* 1/sqrt(HD=16) */

__device__ __forceinline__ float siluf(float x){
  float s = 1.f/(1.f+expf(-x)); return x*s;
}
__device__ __forceinline__ float silugf(float x){
  float s = 1.f/(1.f+expf(-x)); return s*(1.f + x*(1.f-s));
}

// ---------------- 64x64-tile fp32 GEMM, 4x4 micro-tile ----------------
// TRB=0: C[M,Nc] = A[M,K] @ B[K,Nc]   (B row-major [K,Nc])
// TRB=1: C[M,Nc] = A[M,K] @ B^T       (B row-major [Nc,K])
template<int TRB>
__global__ __launch_bounds__(256)
void gemm64(const float* __restrict__ A, const float* __restrict__ B,
            const float* __restrict__ bias, float* __restrict__ C,
            int M, int Nc, int K, int acc)
{
  __shared__ __align__(16) float As[16][68];   // [k][row], padded
  __shared__ __align__(16) float Bs[16][68];   // [k][col], padded
  const int tid = threadIdx.x;
  const int br = blockIdx.y*64, bc = blockIdx.x*64;
  const int rm = (tid>>4)<<2;   // 0..60 step 4
  const int cn = (tid&15)<<2;   // 0..60 step 4
  float c16[4][4] = {};
  for (int k0=0;k0<K;k0+=16){
    #pragma unroll
    for (int p=0;p<4;p++){                // A: 64 rows x 16 k
      int idx = p*256+tid;
      int r = idx>>4, c = idx&15;
      int gr = br+r, gc = k0+c;
      As[c][r] = (gr<M && gc<K)? A[(size_t)gr*K+gc] : 0.f;
    }
    #pragma unroll
    for (int p=0;p<4;p++){                // B: 16 k x 64 cols
      int idx=p*256+tid;
      if (TRB==0){
        int kk = idx>>6, n = idx&63;
        int gk = k0+kk, gn = bc+n;
        Bs[kk][n] = (gk<K && gn<Nc)? B[(size_t)gk*Nc+gn] : 0.f;
      } else {
        int n = idx>>4, c = idx&15;
        int gn = bc+n, gk = k0+c;
        Bs[c][n] = (gn<Nc && gk<K)? B[(size_t)gn*K+gk] : 0.f;
      }
    }
    __syncthreads();
    #pragma unroll
    for (int kk=0;kk<16;kk++){
      const float4 av = *reinterpret_cast<const float4*>(&As[kk][rm]);
      const float4 bv = *reinterpret_cast<const float4*>(&Bs[kk][cn]);
      const float a4[4]={av.x,av.y,av.z,av.w};
      const float b4[4]={bv.x,bv.y,bv.z,bv.w};
      #pragma unroll
      for(int i=0;i<4;i++)
        #pragma unroll
        for(int j=0;j<4;j++) c16[i][j] += a4[i]*b4[j];
    }
    __syncthreads();
  }
  #pragma unroll
  for(int i=0;i<4;i++){
    int r = br+rm+i; if (r>=M) continue;
    #pragma unroll
    for(int j=0;j<4;j++){
      int col = bc+cn+j; if (col>=Nc) continue;
      size_t o = (size_t)r*Nc+col;
      float bv = bias? bias[col]:0.f;
      C[o] = (acc? C[o]:0.f) + c16[i][j] + bv;
    }
  }
}

// ---------------- forward geometry / elementwise ----------------
__global__ void k_edge_geom(const float* __restrict__ pos, const int* __restrict__ ei,
                            float* __restrict__ dv, float* __restrict__ env,
                            float* __restrict__ denv, float* __restrict__ nrbf)
{
  int e = blockIdx.x*256+threadIdx.x; if(e>=EN) return;
  int s = ei[e], t = ei[EN+e];
  float dx=pos[3*s]-pos[3*t], dy=pos[3*s+1]-pos[3*t+1], dz=pos[3*s+2]-pos[3*t+2];
  float d = sqrtf(dx*dx+dy*dy+dz*dz);
  float u = d/CUTF, ev=0.f, dev=0.f;
  if (u<1.f){
    float u2=u*u, u4=u2*u2, u5=u4*u;
    ev  = 1.f - 21.f*u5 + 35.f*u5*u - 15.f*u5*u2;
    dev = (-105.f*u4 + 210.f*u5 - 105.f*u4*u2)/CUTF;
  }
  dv[e]=d; env[e]=ev; denv[e]=dev;
  const float C0 = sqrtf(2.f/CUTF);
  #pragma unroll
  for (int n=0;n<RBFD;n++){
    float wv = (n+1)*PIF/CUTF;
    nrbf[e*RBFD+n] = C0*sinf(wv*d)/d*ev;
  }
}

__global__ void k_scale_ea(const float* __restrict__ ea, const float* __restrict__ env,
                           float* __restrict__ ob)
{
  int i = blockIdx.x*256+threadIdx.x; if(i>=EN*MATD) return;
  ob[i] = ea[i]*env[i/MATD];
}

__global__ void k_ang(const float* __restrict__ pos, const int* __restrict__ ai,
                      const int* __restrict__ aj, const int* __restrict__ ak,
                      float* __restrict__ ang)
{
  int t = blockIdx.x*256+threadIdx.x; if(t>=TN) return;
  int i=ai[t], j=aj[t], k=ak[t];
  float jix=pos[3*i]-pos[3*j], jiy=pos[3*i+1]-pos[3*j+1], jiz=pos[3*i+2]-pos[3*j+2];
  float jkx=pos[3*k]-pos[3*j], jky=pos[3*k+1]-pos[3*j+1], jkz=pos[3*k+2]-pos[3*j+2];
  float cx=jiy*jkz-jiz*jky, cy=jiz*jkx-jix*jkz, cz=jix*jky-jiy*jkx;
  float cn=sqrtf(cx*cx+cy*cy+cz*cz);
  float dt=jix*jkx+jiy*jky+jiz*jkz;
  ang[t]=atan2f(cn,dt);
}

__global__ void k_sbf(const float* __restrict__ ang, const float* __restrict__ nrbf,
                      const int* __restrict__ neo0, float* __restrict__ sbf)
{
  int i = blockIdx.x*256+threadIdx.x; if(i>=TN*SBFW) return;
  int t = i/SBFW, col = i - t*SBFW;
  int l = col>>4, n = col&15;
  int e2 = neo0[t];
  sbf[i] = cosf((float)l*ang[t])*nrbf[e2*RBFD+n];
}

__global__ void k_embx(const int* __restrict__ x, const float* __restrict__ tab,
                       float* __restrict__ embx)
{
  int i = blockIdx.x*256+threadIdx.x; if(i>=NN*EMBD) return;
  int n=i>>7, c=i&127;
  embx[i]=tab[x[n]*EMBD+c];
}

__global__ void k_cat(const float* __restrict__ p1, const float* __restrict__ p2,
                      float* __restrict__ cat)
{
  int i=blockIdx.x*256+threadIdx.x; if(i>=EN*CHD) return;
  int e=i>>8, j=i&255;
  cat[i] = (j<128)? siluf(p1[e*128+j]) : siluf(p2[e*128+j-128]);
}

__global__ void k_silu(const float* __restrict__ in, float* __restrict__ ob, int n)
{
  int i=blockIdx.x*256+threadIdx.x; if(i>=n) return;
  ob[i]=siluf(in[i]);
}

__global__ void k_residual(const float* __restrict__ hin, const float* __restrict__ opre,
                           float* __restrict__ hout)
{
  int i=blockIdx.x*256+threadIdx.x; if(i>=EN*CHD) return;
  hout[i]=hin[i]+siluf(opre[i]);
}

// ---------------- attention (per dst-edge x head; 7 contiguous triplets) ----------------
__global__ void k_attn_fwd(const float* __restrict__ q, const float* __restrict__ kb,
                           const float* __restrict__ vb, const float* __restrict__ esb,
                           const float* __restrict__ eatn, const int* __restrict__ neo0,
                           float* __restrict__ attn, float* __restrict__ agg, int e0)
{
  int idx = blockIdx.x*256+threadIdx.x;
  if (idx>=ECH*HEADS) return;
  int e = e0 + idx/HEADS, h = idx%HEADS;
  int n = e>>3, t0 = e0*7;
  float qv[16], evv[16];
  #pragma unroll
  for (int d=0;d<16;d++){ qv[d]=q[e*CHD+h*16+d]; evv[d]=eatn[n*CHD+h*16+d]; }
  float lg[7]; int src[7];
  for (int jj=0;jj<7;jj++){
    int t=e*7+jj; int sE=neo0[t]; src[jj]=sE;
    const float* ep = esb + (size_t)(t-t0)*CHD + h*16;
    const float* kp = kb + (size_t)sE*CHD + h*16;
    float s=0.f;
    #pragma unroll
    for (int d=0;d<16;d++) s += qv[d]*(kp[d]*ep[d]+evv[d]);
    lg[jj]=s*INVS;
  }
  float m=lg[0];
  for(int jj=1;jj<7;jj++) m=fmaxf(m,lg[jj]);
  float ex[7], den=0.f;
  for(int jj=0;jj<7;jj++){ ex[jj]=expf(lg[jj]-m); den+=ex[jj]; }
  float rd=1.f/(den+1e-16f);
  float av[16];
  #pragma unroll
  for(int d=0;d<16;d++) av[d]=0.f;
  for(int jj=0;jj<7;jj++){
    int t=e*7+jj;
    float at=ex[jj]*rd;
    attn[(size_t)t*HEADS+h]=at;
    const float* ep = esb + (size_t)(t-t0)*CHD + h*16;
    const float* vp = vb + (size_t)src[jj]*CHD + h*16;
    #pragma unroll
    for(int d=0;d<16;d++) av[d]+=at*vp[d]*ep[d];
  }
  #pragma unroll
  for(int d=0;d<16;d++) agg[e*CHD+h*16+d]=av[d];
}

__global__ void k_edge_out(const float* __restrict__ g1pre, const float* __restrict__ w2,
                           const float* __restrict__ b2, const int* __restrict__ eb,
                           float* __restrict__ ob)
{
  int e=blockIdx.x*256+threadIdx.x; if(e>=EN) return;
  float s=b2[0];
  for(int c=0;c<EMBD;c++) s += siluf(g1pre[e*EMBD+c])*w2[c];
  atomicAdd(&ob[eb[e]], s);
}

// ---------------- backward ----------------
__global__ void k_gg1(const float* __restrict__ g1pre, const float* __restrict__ w2,
                      float* __restrict__ gg1)
{
  int i=blockIdx.x*256+threadIdx.x; if(i>=EN*EMBD) return;
  gg1[i]=w2[i&127]*silugf(g1pre[i]);
}

__global__ void k_gopre(const float* __restrict__ gh, const float* __restrict__ opre,
                        float* __restrict__ ob)
{
  int i=blockIdx.x*256+threadIdx.x; if(i>=EN*CHD) return;
  ob[i]=gh[i]*silugf(opre[i]);
}

__global__ void k_attn_bwd_edge(const float* __restrict__ q, const float* __restrict__ kb,
                                const float* __restrict__ vb, const float* __restrict__ esb,
                                const float* __restrict__ eatn, const float* __restrict__ attn,
                                const float* __restrict__ gagg, const int* __restrict__ neo0,
                                float* __restrict__ gq, float* __restrict__ gesb,
                                float* __restrict__ glog, int e0)
{
  int idx=blockIdx.x*256+threadIdx.x;
  if(idx>=ECH*HEADS) return;
  int e=e0+idx/HEADS, h=idx%HEADS;
  int n=e>>3, t0=e0*7;
  float qv[16], evv[16], gv[16];
  #pragma unroll
  for(int d=0;d<16;d++){
    qv[d]=q[e*CHD+h*16+d];
    evv[d]=eatn[n*CHD+h*16+d];
    gv[d]=gagg[e*CHD+h*16+d];
  }
  float ga[7], at[7]; int src[7];
  for(int jj=0;jj<7;jj++){
    int t=e*7+jj; int sE=neo0[t]; src[jj]=sE;
    at[jj]=attn[(size_t)t*HEADS+h];
    const float* ep=esb+(size_t)(t-t0)*CHD+h*16;
    const float* vp=vb+(size_t)sE*CHD+h*16;
    float s=0.f;
    #pragma unroll
    for(int d=0;d<16;d++) s+=gv[d]*vp[d]*ep[d];
    ga[jj]=s;
  }
  float sm=0.f;
  for(int jj=0;jj<7;jj++) sm+=at[jj]*ga[jj];
  float gqv[16];
  #pragma unroll
  for(int d=0;d<16;d++) gqv[d]=0.f;
  for(int jj=0;jj<7;jj++){
    int t=e*7+jj; int sE=src[jj];
    float gl=at[jj]*(ga[jj]-sm);
    glog[(size_t)t*HEADS+h]=gl;
    const float* ep=esb+(size_t)(t-t0)*CHD+h*16;
    const float* kp=kb+(size_t)sE*CHD+h*16;
    const float* vp=vb+(size_t)sE*CHD+h*16;
    float* gp=gesb+(size_t)(t-t0)*CHD+h*16;
    #pragma unroll
    for(int d=0;d<16;d++){
      float es=ep[d], kk=kp[d];
      gqv[d]+=gl*INVS*(kk*es+evv[d]);
      gp[d]=at[jj]*vp[d]*gv[d]+gl*INVS*qv[d]*kk;
    }
  }
  #pragma unroll
  for(int d=0;d<16;d++) gq[e*CHD+h*16+d]=gqv[d];
}

// gather per src edge: its 7 triplets are t = n*56 + a*7 + (b - (b>a)), a != b
__global__ void k_attn_bwd_src(const float* __restrict__ q, const float* __restrict__ esb,
                               const float* __restrict__ attn, const float* __restrict__ gagg,
                               const float* __restrict__ glog,
                               float* __restrict__ gk, float* __restrict__ gv, int e0)
{
  int idx=blockIdx.x*256+threadIdx.x;
  if(idx>=ECH*HEADS) return;
  int e=e0+idx/HEADS, h=idx%HEADS;   // e = src edge
  int n=e>>3, b=e&7, t0=e0*7;
  float gkk[16], gvv[16];
  #pragma unroll
  for(int d=0;d<16;d++){ gkk[d]=0.f; gvv[d]=0.f; }
  for(int a=0;a<8;a++){
    if(a==b) continue;
    int t = n*56 + a*7 + (b>a ? b-1 : b);
    int de = n*8 + a;
    float gl=glog[(size_t)t*HEADS+h]*INVS;
    float at=attn[(size_t)t*HEADS+h];
    const float* ep=esb+(size_t)(t-t0)*CHD+h*16;
    const float* qp=q+(size_t)de*CHD+h*16;
    const float* gp=gagg+(size_t)de*CHD+h*16;
    #pragma unroll
    for(int d=0;d<16;d++){
      float es=ep[d];
      gkk[d]+=gl*qp[d]*es;
      gvv[d]+=at*es*gp[d];
    }
  }
  #pragma unroll
  for(int d=0;d<16;d++){ gk[e*CHD+h*16+d]=gkk[d]; gv[e*CHD+h*16+d]=gvv[d]; }
}

__global__ void k_gp3(float* __restrict__ gh, const float* __restrict__ p3)
{
  int i=blockIdx.x*256+threadIdx.x; if(i>=EN*EMBD) return;
  gh[i]*=silugf(p3[i]);
}

__global__ void k_split(const float* __restrict__ gcat, const float* __restrict__ p1,
                        const float* __restrict__ p2, float* __restrict__ gp1,
                        float* __restrict__ gp2)
{
  int i=blockIdx.x*256+threadIdx.x; if(i>=EN*EMBD) return;
  int e=i>>7, c=i&127;
  gp1[i]=gcat[e*CHD+c]*silugf(p1[i]);
  gp2[i]=gcat[e*CHD+128+c]*silugf(p2[i]);
}

__global__ void k_edge_bwd(const float* __restrict__ geaenv, const float* __restrict__ ea,
                           const float* __restrict__ env, const float* __restrict__ denv,
                           const float* __restrict__ dv, const float* __restrict__ gnr,
                           float* __restrict__ eag, float* __restrict__ gd)
{
  int e=blockIdx.x*256+threadIdx.x; if(e>=EN) return;
  float ev=env[e], dev=denv[e], d=dv[e];
  float gmat=0.f;
  for(int m=0;m<MATD;m++){
    float g=geaenv[e*MATD+m];
    eag[e*MATD+m]=g*ev;
    gmat+=g*ea[e*MATD+m];
  }
  float acc=gmat*dev;
  const float C0=sqrtf(2.f/CUTF);
  for(int n=0;n<RBFD;n++){
    float wv=(n+1)*PIF/CUTF;
    float sn,cs; sincosf(wv*d,&sn,&cs);
    float rb=C0*sn/d;
    float rbp=C0*(wv*cs/d - sn/(d*d));
    acc += gnr[e*RBFD+n]*(rbp*ev+rb*dev);
  }
  gd[e]=acc;
}

__global__ void k_sbf_bwd(const float* __restrict__ gsbf, const float* __restrict__ ang,
                          const float* __restrict__ dv, const float* __restrict__ env,
                          const float* __restrict__ denv, const float* __restrict__ nrbf,
                          const int* __restrict__ neo0, const int* __restrict__ ai,
                          const int* __restrict__ aj, const int* __restrict__ ak,
                          const float* __restrict__ pos,
                          float* __restrict__ gd, float* __restrict__ gpos)
{
  int t=blockIdx.x*256+threadIdx.x; if(t>=TN) return;
  int e2=neo0[t];
  float a=ang[t];
  float rad[16], gr[16];
  #pragma unroll
  for(int n=0;n<16;n++){ rad[n]=nrbf[e2*RBFD+n]; gr[n]=0.f; }
  float gang=0.f;
  for(int l=0;l<7;l++){
    float sl,cl; sincosf((float)l*a,&sl,&cl);
    float srow=0.f;
    #pragma unroll
    for(int n=0;n<16;n++){
      float gs=gsbf[(size_t)t*SBFW+l*16+n];
      gr[n]+=gs*cl;
      srow+=gs*rad[n];
    }
    gang+=-(float)l*sl*srow;
  }
  float d2=dv[e2], ev=env[e2], dev=denv[e2];
  const float C0=sqrtf(2.f/CUTF);
  float gdd=0.f;
  for(int n=0;n<16;n++){
    float wv=(n+1)*PIF/CUTF;
    float sn,cs; sincosf(wv*d2,&sn,&cs);
    float rb=C0*sn/d2;
    float rbp=C0*(wv*cs/d2 - sn/(d2*d2));
    gdd+=gr[n]*(rbp*ev+rb*dev);
  }
  atomicAdd(&gd[e2],gdd);
  // angle -> positions
  int i=ai[t], j=aj[t], k=ak[t];
  float jix=pos[3*i]-pos[3*j], jiy=pos[3*i+1]-pos[3*j+1], jiz=pos[3*i+2]-pos[3*j+2];
  float jkx=pos[3*k]-pos[3*j], jky=pos[3*k+1]-pos[3*j+1], jkz=pos[3*k+2]-pos[3*j+2];
  float cx=jiy*jkz-jiz*jky, cy=jiz*jkx-jix*jkz, cz=jix*jky-jiy*jkx;
  float cn2=cx*cx+cy*cy+cz*cz;
  float cn=sqrtf(cn2);
  float dt=jix*jkx+jiy*jky+jiz*jkz;
  float den=cn2+dt*dt;
  float coef=gang/den;
  float rc=dt/cn;
  float axv=jky*cz-jkz*cy, ayv=jkz*cx-jkx*cz, azv=jkx*cy-jky*cx;  // jk x c
  float bxv=cy*jiz-cz*jiy, byv=cz*jix-cx*jiz, bzv=cx*jiy-cy*jix;  // c x ji
  float gjix=coef*(rc*axv-cn*jkx), gjiy=coef*(rc*ayv-cn*jky), gjiz=coef*(rc*azv-cn*jkz);
  float gjkx=coef*(rc*bxv-cn*jix), gjky=coef*(rc*byv-cn*jiy), gjkz=coef*(rc*bzv-cn*jiz);
  atomicAdd(&gpos[3*i],gjix); atomicAdd(&gpos[3*i+1],gjiy); atomicAdd(&gpos[3*i+2],gjiz);
  atomicAdd(&gpos[3*k],gjkx); atomicAdd(&gpos[3*k+1],gjky); atomicAdd(&gpos[3*k+2],gjkz);
  atomicAdd(&gpos[3*j],-(gjix+gjkx)); atomicAdd(&gpos[3*j+1],-(gjiy+gjky)); atomicAdd(&gpos[3*j+2],-(gjiz+gjkz));
}

__global__ void k_d_bwd(const float* __restrict__ gd, const float* __restrict__ dv,
                        const float* __restrict__ pos, const int* __restrict__ ei,
                        float* __restrict__ gpos)
{
  int e=blockIdx.x*256+threadIdx.x; if(e>=EN) return;
  int s=ei[e], t=ei[EN+e];
  float g=gd[e]/dv[e];
  float dx=pos[3*s]-pos[3*t], dy=pos[3*s+1]-pos[3*t+1], dz=pos[3*s+2]-pos[3*t+2];
  atomicAdd(&gpos[3*s], g*dx); atomicAdd(&gpos[3*s+1], g*dy); atomicAdd(&gpos[3*s+2], g*dz);
  atomicAdd(&gpos[3*t], -g*dx); atomicAdd(&gpos[3*t+1], -g*dy); atomicAdd(&gpos[3*t+2], -g*dz);
}

// contrib[e,a,c] = sum_m G[e,a,c,m]*eag[e,m], summed over 192 edges/graph.
// block = (g, acg of 4, echunk of 48); eag slab staged in LDS; 1 wave per ac.
__global__ __launch_bounds__(256)
void k_einsum2(const float* __restrict__ G_, const float* __restrict__ eag,
               float* __restrict__ gpos)
{
  __shared__ float eL[48*MATD];          // 32448 B
  int bid = blockIdx.x;                   // 32*18*4 = 2304
  int g = bid/72, rem = bid%72;
  int acg = rem>>2, ech = rem&3;
  int e0 = g*192 + ech*48;
  for (int i=threadIdx.x; i<48*MATD; i+=256)
    eL[i] = eag[(size_t)e0*MATD + i];
  __syncthreads();
  int wv = threadIdx.x>>6, lane = threadIdx.x&63;
  int ac = acg*4 + wv;                    // 0..71
  float s=0.f;
  for (int e=0;e<48;e++){
    const float* Gp = G_ + ((size_t)(e0+e)*(AN*3) + ac)*MATD;
    const float* Ep = eL + e*MATD;
    s += Gp[lane]*Ep[lane];
    s += Gp[lane+64]*Ep[lane+64];
    if (lane<41) s += Gp[lane+128]*Ep[lane+128];
  }
  #pragma unroll
  for (int o=32;o>0;o>>=1) s += __shfl_down(s,o,64);
  if (lane==0) atomicAdd(&gpos[g*(AN*3)+ac], s);
}

__global__ void k_force(const float* __restrict__ gpos, float* __restrict__ ob)
{
  int i=blockIdx.x*256+threadIdx.x; if(i>=NN*3) return;
  ob[GN+i]=-gpos[i];
}

extern "C" void kernel_launch(void* const* d_in, const int* in_sizes, int n_in,
                              void* d_out, int out_size, void* d_ws, size_t ws_size,
                              hipStream_t stream)
{
  const int*   x      = (const int*)d_in[0];
  const int*   ei     = (const int*)d_in[1];
  const int*   neo    = (const int*)d_in[2];
  const int*   ai     = (const int*)d_in[3];
  const int*   aj     = (const int*)d_in[4];
  const int*   ak     = (const int*)d_in[5];
  const int*   eb     = (const int*)d_in[6];
  const float* pos    = (const float*)d_in[8];
  const float* eattr  = (const float*)d_in[9];
  const float* eagrad = (const float*)d_in[10];
  const float* etab   = (const float*)d_in[11];
  const float* matW   = (const float*)d_in[12];
  const float* matB   = (const float*)d_in[13];
  const float* rbfW   = (const float*)d_in[14];
  const float* rbfB   = (const float*)d_in[15];
  const float* embtW  = (const float*)d_in[16];
  const float* embtB  = (const float*)d_in[17];
  const float* inW    = (const float*)d_in[18];
  const float* inB    = (const float*)d_in[19];
  const float* Wq     = (const float*)d_in[20];
  const float* Wk     = (const float*)d_in[21];
  const float* Wv     = (const float*)d_in[22];
  const float* Wo     = (const float*)d_in[23];
  const float* bo     = (const float*)d_in[24];
  const float* Wsbf   = (const float*)d_in[25];
  const float* Weat   = (const float*)d_in[26];
  const float* o1W    = (const float*)d_in[27];
  const float* o1B    = (const float*)d_in[28];
  const float* o2W    = (const float*)d_in[29];
  const float* o2B    = (const float*)d_in[30];
  float* out = (float*)d_out;
  (void)in_sizes; (void)n_in; (void)out_size; (void)ws_size;

  float* w=(float*)d_ws;
  size_t off=0;
  auto A=[&](size_t n){ float* p=w+off; off+=n; return p; };
  float* dv    = A(EN);
  float* env   = A(EN);
  float* denv  = A(EN);
  float* gd    = A(EN);
  float* nrbf  = A((size_t)EN*RBFD);
  float* gnr   = A((size_t)EN*RBFD);
  float* easc  = A((size_t)EN*MATD);
  float* geaenv= A((size_t)EN*MATD);
  float* eag   = A((size_t)EN*MATD);
  float* p1    = A((size_t)EN*EMBD);
  float* p2    = A((size_t)EN*EMBD);
  float* p3    = A((size_t)EN*EMBD);
  float* hpre  = A((size_t)EN*EMBD);
  float* g1pre = A((size_t)EN*EMBD);
  float* gg1   = A((size_t)EN*EMBD);   // later reused as grad_p1
  float* ghpre = A((size_t)EN*EMBD);
  float* gp2   = A((size_t)EN*EMBD);
  float* hlay  = A((size_t)5*EN*CHD);
  float* cat   = A((size_t)EN*CHD);
  float* qb    = A((size_t)EN*CHD);
  float* kb    = A((size_t)EN*CHD);
  float* vb    = A((size_t)EN*CHD);
  float* gq    = A((size_t)EN*CHD);
  float* gk    = A((size_t)EN*CHD);
  float* gv    = A((size_t)EN*CHD);
  float* sc1   = A((size_t)EN*CHD);    // gopre
  float* sc2   = A((size_t)EN*CHD);    // agg fwd / grad_agg bwd / grad_cat tail
  float* gradh = A((size_t)EN*CHD);
  float* opre  = A((size_t)4*EN*CHD);
  float* sbf   = A((size_t)TN*SBFW);
  float* gsbf  = A((size_t)TN*SBFW);
  float* angb  = A(TN);
  float* attn  = A((size_t)4*TN*HEADS);
  float* glog  = A((size_t)TN*HEADS);
  float* esbb  = A((size_t)TCH*CHD);
  float* gesbb = A((size_t)TCH*CHD);
  float* eatn  = A((size_t)NN*CHD);
  float* embx  = A((size_t)NN*EMBD);
  float* gpos  = A((size_t)NN*3);

  hipMemsetAsync(out, 0, GN*sizeof(float), stream);
  hipMemsetAsync(gsbf, 0, (size_t)TN*SBFW*sizeof(float), stream);
  hipMemsetAsync(gpos, 0, (size_t)NN*3*sizeof(float), stream);

  auto gemm_nn=[&](const float*Ag,const float*Bg,const float*bias,float*Cg,int M,int Nc,int K,int acc){
    hipLaunchKernelGGL((gemm64<0>), dim3((Nc+63)/64,(M+63)/64), dim3(256),0,stream, Ag,Bg,bias,Cg,M,Nc,K,acc);
  };
  auto gemm_nt=[&](const float*Ag,const float*Bg,const float*bias,float*Cg,int M,int Nc,int K,int acc){
    hipLaunchKernelGGL((gemm64<1>), dim3((Nc+63)/64,(M+63)/64), dim3(256),0,stream, Ag,Bg,bias,Cg,M,Nc,K,acc);
  };

  // ---------- forward ----------
  hipLaunchKernelGGL(k_edge_geom, dim3((EN+255)/256),dim3(256),0,stream, pos,ei,dv,env,denv,nrbf);
  hipLaunchKernelGGL(k_scale_ea, dim3((EN*MATD+255)/256),dim3(256),0,stream, eattr,env,easc);
  hipLaunchKernelGGL(k_ang, dim3((TN+255)/256),dim3(256),0,stream, pos,ai,aj,ak,angb);
  hipLaunchKernelGGL(k_sbf, dim3((TN*SBFW+255)/256),dim3(256),0,stream, angb,nrbf,neo,sbf);
  hipLaunchKernelGGL(k_embx, dim3((NN*EMBD+255)/256),dim3(256),0,stream, x,etab,embx);

  gemm_nn(easc, matW, matB, p1, EN, EMBD, MATD, 0);
  gemm_nn(nrbf, rbfW, rbfB, p2, EN, EMBD, RBFD, 0);
  hipLaunchKernelGGL(k_cat, dim3((EN*CHD+255)/256),dim3(256),0,stream, p1,p2,cat);
  gemm_nn(cat, embtW, embtB, p3, EN, EMBD, CHD, 0);
  hipLaunchKernelGGL(k_silu, dim3((EN*EMBD+255)/256),dim3(256),0,stream, p3,hpre,EN*EMBD);
  gemm_nn(hpre, inW, inB, hlay, EN, CHD, EMBD, 0);

  for (int l=0;l<LN;l++){
    const float* hl=hlay+(size_t)l*EN*CHD;
    gemm_nn(hl, Wq+(size_t)l*CHD*CHD, nullptr, qb, EN, CHD, CHD, 0);
    gemm_nn(hl, Wk+(size_t)l*CHD*CHD, nullptr, kb, EN, CHD, CHD, 0);
    gemm_nn(hl, Wv+(size_t)l*CHD*CHD, nullptr, vb, EN, CHD, CHD, 0);
    gemm_nn(embx, Weat+(size_t)l*EMBD*CHD, nullptr, eatn, NN, CHD, EMBD, 0);
    float* attl = attn+(size_t)l*TN*HEADS;
    for (int c=0;c<NCHK;c++){
      int e0=c*ECH, t0=e0*7;
      gemm_nn(sbf+(size_t)t0*SBFW, Wsbf+(size_t)l*SBFW*CHD, nullptr, esbb, TCH, CHD, SBFW, 0);
      hipLaunchKernelGGL(k_attn_fwd, dim3((ECH*HEADS+255)/256),dim3(256),0,stream,
                         qb,kb,vb,esbb,eatn,neo,attl,sc2,e0);
    }
    float* opl=opre+(size_t)l*EN*CHD;
    gemm_nn(sc2, Wo+(size_t)l*CHD*CHD, bo+(size_t)l*CHD, opl, EN, CHD, CHD, 0);
    hipLaunchKernelGGL(k_residual, dim3((EN*CHD+255)/256),dim3(256),0,stream,
                       hl,opl,hlay+(size_t)(l+1)*EN*CHD);
  }
  const float* h4=hlay+(size_t)4*EN*CHD;
  gemm_nn(h4, o1W, o1B, g1pre, EN, EMBD, CHD, 0);
  hipLaunchKernelGGL(k_edge_out, dim3((EN+255)/256),dim3(256),0,stream, g1pre,o2W,o2B,eb,out);

  // ---------- backward ----------
  hipLaunchKernelGGL(k_gg1, dim3((EN*EMBD+255)/256),dim3(256),0,stream, g1pre,o2W,gg1);
  gemm_nt(gg1, o1W, nullptr, gradh, EN, CHD, EMBD, 0);

  for (int l=LN-1;l>=0;l--){
    const float* hl=hlay+(size_t)l*EN*CHD;
    float* opl=opre+(size_t)l*EN*CHD;
    float* attl=attn+(size_t)l*TN*HEADS;
    hipLaunchKernelGGL(k_gopre, dim3((EN*CHD+255)/256),dim3(256),0,stream, gradh,opl,sc1);
    gemm_nt(sc1, Wo+(size_t)l*CHD*CHD, nullptr, sc2, EN, CHD, CHD, 0);   // grad_agg
    gemm_nn(hl, Wq+(size_t)l*CHD*CHD, nullptr, qb, EN, CHD, CHD, 0);
    gemm_nn(hl, Wk+(size_t)l*CHD*CHD, nullptr, kb, EN, CHD, CHD, 0);
    gemm_nn(hl, Wv+(size_t)l*CHD*CHD, nullptr, vb, EN, CHD, CHD, 0);
    gemm_nn(embx, Weat+(size_t)l*EMBD*CHD, nullptr, eatn, NN, CHD, EMBD, 0);
    for (int c=0;c<NCHK;c++){
      int e0=c*ECH, t0=e0*7;
      gemm_nn(sbf+(size_t)t0*SBFW, Wsbf+(size_t)l*SBFW*CHD, nullptr, esbb, TCH, CHD, SBFW, 0);
      hipLaunchKernelGGL(k_attn_bwd_edge, dim3((ECH*HEADS+255)/256),dim3(256),0,stream,
                         qb,kb,vb,esbb,eatn,attl,sc2,neo,gq,gesbb,glog,e0);
      hipLaunchKernelGGL(k_attn_bwd_src, dim3((ECH*HEADS+255)/256),dim3(256),0,stream,
                         qb,esbb,attl,sc2,glog,gk,gv,e0);
      gemm_nt(gesbb, Wsbf+(size_t)l*SBFW*CHD, nullptr, gsbf+(size_t)t0*SBFW, TCH, SBFW, CHD, 1);
    }
    gemm_nt(gq, Wq+(size_t)l*CHD*CHD, nullptr, gradh, EN, CHD, CHD, 1);
    gemm_nt(gk, Wk+(size_t)l*CHD*CHD, nullptr, gradh, EN, CHD, CHD, 1);
    gemm_nt(gv, Wv+(size_t)l*CHD*CHD, nullptr, gradh, EN, CHD, CHD, 1);
  }

  gemm_nt(gradh, inW, nullptr, ghpre, EN, EMBD, CHD, 0);
  hipLaunchKernelGGL(k_gp3, dim3((EN*EMBD+255)/256),dim3(256),0,stream, ghpre,p3);
  gemm_nt(ghpre, embtW, nullptr, sc2, EN, CHD, EMBD, 0);  // grad_cat
  hipLaunchKernelGGL(k_split, dim3((EN*EMBD+255)/256),dim3(256),0,stream, sc2,p1,p2,gg1,gp2);
  gemm_nt(gp2, rbfW, nullptr, gnr, EN, RBFD, EMBD, 0);
  gemm_nt(gg1, matW, nullptr, geaenv, EN, MATD, EMBD, 0);
  hipLaunchKernelGGL(k_edge_bwd, dim3((EN+255)/256),dim3(256),0,stream,
                     geaenv,eattr,env,denv,dv,gnr,eag,gd);
  hipLaunchKernelGGL(k_sbf_bwd, dim3((TN+255)/256),dim3(256),0,stream,
                     gsbf,angb,dv,env,denv,nrbf,neo,ai,aj,ak,pos,gd,gpos);
  hipLaunchKernelGGL(k_d_bwd, dim3((EN+255)/256),dim3(256),0,stream, gd,dv,pos,ei,gpos);
  hipLaunchKernelGGL(k_einsum2, dim3(2304),dim3(256),0,stream, eagrad,eag,gpos);
  hipLaunchKernelGGL(k_force, dim3((NN*3+255)/256),dim3(256),0,stream, gpos,out);
}

// Round 4
// 3437.933 us; speedup vs baseline: 1.7063x; 1.7044x over previous
//
#include <hip/hip_runtime.h>
#include <math.h>

#define GN 32
#define AN 24
#define NN 768
#define EN 6144
#define TN 43008
#define MATD 169
#define EMBD 128
#define RBFD 16
#define SBFW 112
#define HEADS 16
#define CHD 256
#define LN 4
#define CUTF 5.0f
#define PIF 3.14159265358979323846f
#define INVS 0.25f         /* 1/sqrt(HD=16) */

__device__ __forceinline__ float siluf(float x){
  float s = 1.f/(1.f+expf(-x)); return x*s;
}
__device__ __forceinline__ float silugf(float x){
  float s = 1.f/(1.f+expf(-x)); return s*(1.f + x*(1.f-s));
}

// ---------------- 64x64-tile fp32 GEMM, 4x4 micro-tile, fused variants ----
// TRB: 0 C=A@B (B [K,Nc]); 1 C=A@B^T (B [Nc,K])
// SEL: 0 none; 1 nn with B chosen by output-col block of 256 (Nc=768);
//      2 nt-style with B chosen by k block of 256 (K=768), B [256,256]
// AMOD (A-load): 0 none; 1 silu(A); 2 silu(cat(aux0,aux1)) K=256;
//      3 A*silugf(aux0); 4 silugf(A)*aux0[k]; 5 A*aux0[row]
// EPI: 0 (acc?C:0)+v+bias; 1 C=pre, out2=hin+silu(pre);
//      2 C=v*silugf(eaux0); 3 split cols: gp1/gp2 = v*silugf(p1/p2)
template<int TRB,int SEL,int AMOD,int EPI>
__global__ __launch_bounds__(256)
void gemmX(const float* __restrict__ A,
           const float* __restrict__ B0, const float* __restrict__ B1,
           const float* __restrict__ B2,
           const float* __restrict__ bias, float* __restrict__ C,
           float* __restrict__ out2,
           const float* __restrict__ aux0, const float* __restrict__ aux1,
           const float* __restrict__ eaux0, const float* __restrict__ eaux1,
           const float* __restrict__ hin,
           int M, int Nc, int K, int acc, size_t sA, size_t sB, size_t sC)
{
  const int z = blockIdx.z;
  A += (size_t)z*sA; C += (size_t)z*sC;
  const float* Bz = B0 + (size_t)z*sB;
  __shared__ __align__(16) float As[16][68];
  __shared__ __align__(16) float Bs[16][68];
  const int tid=threadIdx.x;
  const int br=blockIdx.y*64, bc=blockIdx.x*64;
  const int rm=(tid>>4)<<2, cn=(tid&15)<<2;
  float c16[4][4]={};
  for(int k0=0;k0<K;k0+=16){
    #pragma unroll
    for(int p=0;p<4;p++){
      int idx=p*256+tid; int r=idx>>4,c=idx&15;
      int gr=br+r, gc=k0+c;
      float v=0.f;
      if(gr<M&&gc<K){
        if(AMOD==0)      v=A[(size_t)gr*K+gc];
        else if(AMOD==1) v=siluf(A[(size_t)gr*K+gc]);
        else if(AMOD==2) v=siluf((gc<128?aux0:aux1)[(size_t)gr*128+(gc&127)]);
        else if(AMOD==3) v=A[(size_t)gr*K+gc]*silugf(aux0[(size_t)gr*K+gc]);
        else if(AMOD==4) v=silugf(A[(size_t)gr*K+gc])*aux0[gc];
        else             v=A[(size_t)gr*K+gc]*aux0[gr];
      }
      As[c][r]=v;
    }
    #pragma unroll
    for(int p=0;p<4;p++){
      int idx=p*256+tid;
      float v=0.f;
      if(SEL==1){
        int kk=idx>>6, n=idx&63;
        int gk=k0+kk, gn=bc+n;
        const float* Bp=(bc<256)?B0:(bc<512)?B1:B2;
        if(gk<K&&gn<Nc) v=Bp[(size_t)gk*256+(gn&255)];
        Bs[kk][n]=v;
      } else if(SEL==2){
        int n=idx>>4, c=idx&15;
        int gn=bc+n, gk=k0+c;
        const float* Bp=(k0<256)?B0:(k0<512)?B1:B2;
        if(gn<Nc&&gk<K) v=Bp[(size_t)gn*256+(gk&255)];
        Bs[c][n]=v;
      } else if(TRB==0){
        int kk=idx>>6, n=idx&63;
        int gk=k0+kk, gn=bc+n;
        if(gk<K&&gn<Nc) v=Bz[(size_t)gk*Nc+gn];
        Bs[kk][n]=v;
      } else {
        int n=idx>>4, c=idx&15;
        int gn=bc+n, gk=k0+c;
        if(gn<Nc&&gk<K) v=Bz[(size_t)gn*K+gk];
        Bs[c][n]=v;
      }
    }
    __syncthreads();
    #pragma unroll
    for(int kk=0;kk<16;kk++){
      float4 av=*reinterpret_cast<const float4*>(&As[kk][rm]);
      float4 bv=*reinterpret_cast<const float4*>(&Bs[kk][cn]);
      float a4[4]={av.x,av.y,av.z,av.w}, b4[4]={bv.x,bv.y,bv.z,bv.w};
      #pragma unroll
      for(int i=0;i<4;i++)
        #pragma unroll
        for(int j=0;j<4;j++) c16[i][j]+=a4[i]*b4[j];
    }
    __syncthreads();
  }
  #pragma unroll
  for(int i=0;i<4;i++){
    int r=br+rm+i; if(r>=M) continue;
    #pragma unroll
    for(int j=0;j<4;j++){
      int col=bc+cn+j; if(col>=Nc) continue;
      size_t o=(size_t)r*Nc+col;
      float v=c16[i][j];
      if(EPI==0){
        float bb=bias?bias[col]:0.f;
        C[o]=(acc?C[o]:0.f)+v+bb;
      } else if(EPI==1){
        float pre=v+(bias?bias[col]:0.f);
        C[o]=pre;
        out2[o]=hin[o]+siluf(pre);
      } else if(EPI==2){
        C[o]=v*silugf(eaux0[o]);
      } else {
        size_t oo=(size_t)r*128+(col&127);
        if(col<128) C[oo]=v*silugf(eaux0[oo]);
        else        out2[oo]=v*silugf(eaux1[oo]);
      }
    }
  }
}

// ---------------- init (replaces 3 memsets) ----------------
__global__ void k_init(float* __restrict__ out, float* __restrict__ gsbf,
                       float* __restrict__ gpos)
{
  int i=blockIdx.x*256+threadIdx.x;
  if(i<TN*SBFW) gsbf[i]=0.f;
  if(i<GN) out[i]=0.f;
  if(i<NN*3) gpos[i]=0.f;
}

// ---------------- forward geometry / elementwise ----------------
__global__ void k_edge_geom(const float* __restrict__ pos, const int* __restrict__ ei,
                            float* __restrict__ dv, float* __restrict__ env,
                            float* __restrict__ denv, float* __restrict__ nrbf)
{
  int e = blockIdx.x*256+threadIdx.x; if(e>=EN) return;
  int s = ei[e], t = ei[EN+e];
  float dx=pos[3*s]-pos[3*t], dy=pos[3*s+1]-pos[3*t+1], dz=pos[3*s+2]-pos[3*t+2];
  float d = sqrtf(dx*dx+dy*dy+dz*dz);
  float u = d/CUTF, ev=0.f, dev=0.f;
  if (u<1.f){
    float u2=u*u, u4=u2*u2, u5=u4*u;
    ev  = 1.f - 21.f*u5 + 35.f*u5*u - 15.f*u5*u2;
    dev = (-105.f*u4 + 210.f*u5 - 105.f*u4*u2)/CUTF;
  }
  dv[e]=d; env[e]=ev; denv[e]=dev;
  const float C0 = sqrtf(2.f/CUTF);
  #pragma unroll
  for (int n=0;n<RBFD;n++){
    float wv = (n+1)*PIF/CUTF;
    nrbf[e*RBFD+n] = C0*sinf(wv*d)/d*ev;
  }
}

__global__ void k_ang(const float* __restrict__ pos, const int* __restrict__ ai,
                      const int* __restrict__ aj, const int* __restrict__ ak,
                      float* __restrict__ ang)
{
  int t = blockIdx.x*256+threadIdx.x; if(t>=TN) return;
  int i=ai[t], j=aj[t], k=ak[t];
  float jix=pos[3*i]-pos[3*j], jiy=pos[3*i+1]-pos[3*j+1], jiz=pos[3*i+2]-pos[3*j+2];
  float jkx=pos[3*k]-pos[3*j], jky=pos[3*k+1]-pos[3*j+1], jkz=pos[3*k+2]-pos[3*j+2];
  float cx=jiy*jkz-jiz*jky, cy=jiz*jkx-jix*jkz, cz=jix*jky-jiy*jkx;
  float cn=sqrtf(cx*cx+cy*cy+cz*cz);
  float dt=jix*jkx+jiy*jky+jiz*jkz;
  ang[t]=atan2f(cn,dt);
}

__global__ void k_sbf(const float* __restrict__ ang, const float* __restrict__ nrbf,
                      const int* __restrict__ neo0, float* __restrict__ sbf)
{
  int i = blockIdx.x*256+threadIdx.x; if(i>=TN*SBFW) return;
  int t = i/SBFW, col = i - t*SBFW;
  int l = col>>4, n = col&15;
  int e2 = neo0[t];
  sbf[i] = cosf((float)l*ang[t])*nrbf[e2*RBFD+n];
}

__global__ void k_embx(const int* __restrict__ x, const float* __restrict__ tab,
                       float* __restrict__ embx)
{
  int i = blockIdx.x*256+threadIdx.x; if(i>=NN*EMBD) return;
  int n=i>>7, c=i&127;
  embx[i]=tab[x[n]*EMBD+c];
}

// ---------------- attention (per dst-edge x head; 7 contiguous triplets) ---
// qkv packed [E, 768] = q|k|v
__global__ void k_attn_fwd(const float* __restrict__ qkv, const float* __restrict__ esb,
                           const float* __restrict__ eatn, const int* __restrict__ neo0,
                           float* __restrict__ attn, float* __restrict__ agg)
{
  int idx = blockIdx.x*256+threadIdx.x;
  if (idx>=EN*HEADS) return;
  int e = idx/HEADS, h = idx%HEADS;
  int n = e>>3;
  float qv[16], evv[16];
  #pragma unroll
  for (int d=0;d<16;d++){
    qv[d]=qkv[(size_t)e*768+h*16+d];
    evv[d]=eatn[(size_t)n*CHD+h*16+d];
  }
  float lg[7]; int src[7];
  for (int jj=0;jj<7;jj++){
    int t=e*7+jj; int sE=neo0[t]; src[jj]=sE;
    const float* ep = esb + (size_t)t*CHD + h*16;
    const float* kp = qkv + (size_t)sE*768 + 256 + h*16;
    float s=0.f;
    #pragma unroll
    for (int d=0;d<16;d++) s += qv[d]*(kp[d]*ep[d]+evv[d]);
    lg[jj]=s*INVS;
  }
  float m=lg[0];
  for(int jj=1;jj<7;jj++) m=fmaxf(m,lg[jj]);
  float ex[7], den=0.f;
  for(int jj=0;jj<7;jj++){ ex[jj]=expf(lg[jj]-m); den+=ex[jj]; }
  float rd=1.f/(den+1e-16f);
  float av[16];
  #pragma unroll
  for(int d=0;d<16;d++) av[d]=0.f;
  for(int jj=0;jj<7;jj++){
    int t=e*7+jj;
    float at=ex[jj]*rd;
    attn[(size_t)t*HEADS+h]=at;
    const float* ep = esb + (size_t)t*CHD + h*16;
    const float* vp = qkv + (size_t)src[jj]*768 + 512 + h*16;
    #pragma unroll
    for(int d=0;d<16;d++) av[d]+=at*vp[d]*ep[d];
  }
  #pragma unroll
  for(int d=0;d<16;d++) agg[(size_t)e*CHD+h*16+d]=av[d];
}

__global__ void k_edge_out(const float* __restrict__ g1pre, const float* __restrict__ w2,
                           const float* __restrict__ b2, const int* __restrict__ eb,
                           float* __restrict__ ob)
{
  int e=blockIdx.x*256+threadIdx.x; if(e>=EN) return;
  float s=b2[0];
  for(int c=0;c<EMBD;c++) s += siluf(g1pre[e*EMBD+c])*w2[c];
  atomicAdd(&ob[eb[e]], s);
}

// ---------------- backward attention ----------------
__global__ void k_attn_bwd_edge(const float* __restrict__ qkv, const float* __restrict__ esb,
                                const float* __restrict__ eatn, const float* __restrict__ attn,
                                const float* __restrict__ gagg, const int* __restrict__ neo0,
                                float* __restrict__ gqkv, float* __restrict__ gesb,
                                float* __restrict__ glog)
{
  int idx=blockIdx.x*256+threadIdx.x;
  if(idx>=EN*HEADS) return;
  int e=idx/HEADS, h=idx%HEADS;
  int n=e>>3;
  float qv[16], evv[16], gv[16];
  #pragma unroll
  for(int d=0;d<16;d++){
    qv[d]=qkv[(size_t)e*768+h*16+d];
    evv[d]=eatn[(size_t)n*CHD+h*16+d];
    gv[d]=gagg[(size_t)e*CHD+h*16+d];
  }
  float ga[7], at[7]; int src[7];
  for(int jj=0;jj<7;jj++){
    int t=e*7+jj; int sE=neo0[t]; src[jj]=sE;
    at[jj]=attn[(size_t)t*HEADS+h];
    const float* ep=esb+(size_t)t*CHD+h*16;
    const float* vp=qkv+(size_t)sE*768+512+h*16;
    float s=0.f;
    #pragma unroll
    for(int d=0;d<16;d++) s+=gv[d]*vp[d]*ep[d];
    ga[jj]=s;
  }
  float sm=0.f;
  for(int jj=0;jj<7;jj++) sm+=at[jj]*ga[jj];
  float gqv[16];
  #pragma unroll
  for(int d=0;d<16;d++) gqv[d]=0.f;
  for(int jj=0;jj<7;jj++){
    int t=e*7+jj; int sE=src[jj];
    float gl=at[jj]*(ga[jj]-sm);
    glog[(size_t)t*HEADS+h]=gl;
    const float* ep=esb+(size_t)t*CHD+h*16;
    const float* kp=qkv+(size_t)sE*768+256+h*16;
    const float* vp=qkv+(size_t)sE*768+512+h*16;
    float* gp=gesb+(size_t)t*CHD+h*16;
    #pragma unroll
    for(int d=0;d<16;d++){
      float es=ep[d], kk=kp[d];
      gqv[d]+=gl*INVS*(kk*es+evv[d]);
      gp[d]=at[jj]*vp[d]*gv[d]+gl*INVS*qv[d]*kk;
    }
  }
  #pragma unroll
  for(int d=0;d<16;d++) gqkv[(size_t)e*768+h*16+d]=gqv[d];
}

// per src edge: its 7 triplets are t = n*56 + a*7 + (b - (b>a)), a != b
__global__ void k_attn_bwd_src(const float* __restrict__ qkv, const float* __restrict__ esb,
                               const float* __restrict__ attn, const float* __restrict__ gagg,
                               const float* __restrict__ glog, float* __restrict__ gqkv)
{
  int idx=blockIdx.x*256+threadIdx.x;
  if(idx>=EN*HEADS) return;
  int e=idx/HEADS, h=idx%HEADS;   // e = src edge
  int n=e>>3, b=e&7;
  float gkk[16], gvv[16];
  #pragma unroll
  for(int d=0;d<16;d++){ gkk[d]=0.f; gvv[d]=0.f; }
  for(int a=0;a<8;a++){
    if(a==b) continue;
    int t = n*56 + a*7 + (b>a ? b-1 : b);
    int de = n*8 + a;
    float gl=glog[(size_t)t*HEADS+h]*INVS;
    float at=attn[(size_t)t*HEADS+h];
    const float* ep=esb+(size_t)t*CHD+h*16;
    const float* qp=qkv+(size_t)de*768+h*16;
    const float* gp=gagg+(size_t)de*CHD+h*16;
    #pragma unroll
    for(int d=0;d<16;d++){
      float es=ep[d];
      gkk[d]+=gl*qp[d]*es;
      gvv[d]+=at*es*gp[d];
    }
  }
  #pragma unroll
  for(int d=0;d<16;d++){
    gqkv[(size_t)e*768+256+h*16+d]=gkk[d];
    gqkv[(size_t)e*768+512+h*16+d]=gvv[d];
  }
}

// ---------------- backward tail ----------------
__global__ void k_edge_bwd(const float* __restrict__ geaenv, const float* __restrict__ ea,
                           const float* __restrict__ env, const float* __restrict__ denv,
                           const float* __restrict__ dv, const float* __restrict__ gnr,
                           float* __restrict__ eag, float* __restrict__ gd)
{
  int e=blockIdx.x*256+threadIdx.x; if(e>=EN) return;
  float ev=env[e], dev=denv[e], d=dv[e];
  float gmat=0.f;
  for(int m=0;m<MATD;m++){
    float g=geaenv[e*MATD+m];
    eag[e*MATD+m]=g*ev;
    gmat+=g*ea[e*MATD+m];
  }
  float acc=gmat*dev;
  const float C0=sqrtf(2.f/CUTF);
  for(int n=0;n<RBFD;n++){
    float wv=(n+1)*PIF/CUTF;
    float sn,cs; sincosf(wv*d,&sn,&cs);
    float rb=C0*sn/d;
    float rbp=C0*(wv*cs/d - sn/(d*d));
    acc += gnr[e*RBFD+n]*(rbp*ev+rb*dev);
  }
  gd[e]=acc;
}

__global__ void k_sbf_bwd(const float* __restrict__ gsbf, const float* __restrict__ ang,
                          const float* __restrict__ dv, const float* __restrict__ env,
                          const float* __restrict__ denv, const float* __restrict__ nrbf,
                          const int* __restrict__ neo0, const int* __restrict__ ai,
                          const int* __restrict__ aj, const int* __restrict__ ak,
                          const float* __restrict__ pos,
                          float* __restrict__ gd, float* __restrict__ gpos)
{
  int t=blockIdx.x*256+threadIdx.x; if(t>=TN) return;
  int e2=neo0[t];
  float a=ang[t];
  float rad[16], gr[16];
  #pragma unroll
  for(int n=0;n<16;n++){ rad[n]=nrbf[e2*RBFD+n]; gr[n]=0.f; }
  float gang=0.f;
  for(int l=0;l<7;l++){
    float sl,cl; sincosf((float)l*a,&sl,&cl);
    float srow=0.f;
    #pragma unroll
    for(int n=0;n<16;n++){
      float gs=gsbf[(size_t)t*SBFW+l*16+n];
      gr[n]+=gs*cl;
      srow+=gs*rad[n];
    }
    gang+=-(float)l*sl*srow;
  }
  float d2=dv[e2], ev=env[e2], dev=denv[e2];
  const float C0=sqrtf(2.f/CUTF);
  float gdd=0.f;
  for(int n=0;n<16;n++){
    float wv=(n+1)*PIF/CUTF;
    float sn,cs; sincosf(wv*d2,&sn,&cs);
    float rb=C0*sn/d2;
    float rbp=C0*(wv*cs/d2 - sn/(d2*d2));
    gdd+=gr[n]*(rbp*ev+rb*dev);
  }
  atomicAdd(&gd[e2],gdd);
  int i=ai[t], j=aj[t], k=ak[t];
  float jix=pos[3*i]-pos[3*j], jiy=pos[3*i+1]-pos[3*j+1], jiz=pos[3*i+2]-pos[3*j+2];
  float jkx=pos[3*k]-pos[3*j], jky=pos[3*k+1]-pos[3*j+1], jkz=pos[3*k+2]-pos[3*j+2];
  float cx=jiy*jkz-jiz*jky, cy=jiz*jkx-jix*jkz, cz=jix*jky-jiy*jkx;
  float cn2=cx*cx+cy*cy+cz*cz;
  float cn=sqrtf(cn2);
  float dt=jix*jkx+jiy*jky+jiz*jkz;
  float den=cn2+dt*dt;
  float coef=gang/den;
  float rc=dt/cn;
  float axv=jky*cz-jkz*cy, ayv=jkz*cx-jkx*cz, azv=jkx*cy-jky*cx;  // jk x c
  float bxv=cy*jiz-cz*jiy, byv=cz*jix-cx*jiz, bzv=cx*jiy-cy*jix;  // c x ji
  float gjix=coef*(rc*axv-cn*jkx), gjiy=coef*(rc*ayv-cn*jky), gjiz=coef*(rc*azv-cn*jkz);
  float gjkx=coef*(rc*bxv-cn*jix), gjky=coef*(rc*byv-cn*jiy), gjkz=coef*(rc*bzv-cn*jiz);
  atomicAdd(&gpos[3*i],gjix); atomicAdd(&gpos[3*i+1],gjiy); atomicAdd(&gpos[3*i+2],gjiz);
  atomicAdd(&gpos[3*k],gjkx); atomicAdd(&gpos[3*k+1],gjky); atomicAdd(&gpos[3*k+2],gjkz);
  atomicAdd(&gpos[3*j],-(gjix+gjkx)); atomicAdd(&gpos[3*j+1],-(gjiy+gjky)); atomicAdd(&gpos[3*j+2],-(gjiz+gjkz));
}

__global__ void k_d_bwd(const float* __restrict__ gd, const float* __restrict__ dv,
                        const float* __restrict__ pos, const int* __restrict__ ei,
                        float* __restrict__ gpos)
{
  int e=blockIdx.x*256+threadIdx.x; if(e>=EN) return;
  int s=ei[e], t=ei[EN+e];
  float g=gd[e]/dv[e];
  float dx=pos[3*s]-pos[3*t], dy=pos[3*s+1]-pos[3*t+1], dz=pos[3*s+2]-pos[3*t+2];
  atomicAdd(&gpos[3*s], g*dx); atomicAdd(&gpos[3*s+1], g*dy); atomicAdd(&gpos[3*s+2], g*dz);
  atomicAdd(&gpos[3*t], -g*dx); atomicAdd(&gpos[3*t+1], -g*dy); atomicAdd(&gpos[3*t+2], -g*dz);
}

// contrib[e,a,c] = sum_m G[e,a,c,m]*eag[e,m], summed over 192 edges/graph.
__global__ __launch_bounds__(256)
void k_einsum2(const float* __restrict__ G_, const float* __restrict__ eag,
               float* __restrict__ gpos)
{
  __shared__ float eL[48*MATD];
  int bid = blockIdx.x;                   // 32*18*4 = 2304
  int g = bid/72, rem = bid%72;
  int acg = rem>>2, ech = rem&3;
  int e0 = g*192 + ech*48;
  for (int i=threadIdx.x; i<48*MATD; i+=256)
    eL[i] = eag[(size_t)e0*MATD + i];
  __syncthreads();
  int wv = threadIdx.x>>6, lane = threadIdx.x&63;
  int ac = acg*4 + wv;
  float s=0.f;
  for (int e=0;e<48;e++){
    const float* Gp = G_ + ((size_t)(e0+e)*(AN*3) + ac)*MATD;
    const float* Ep = eL + e*MATD;
    s += Gp[lane]*Ep[lane];
    s += Gp[lane+64]*Ep[lane+64];
    if (lane<41) s += Gp[lane+128]*Ep[lane+128];
  }
  #pragma unroll
  for (int o=32;o>0;o>>=1) s += __shfl_down(s,o,64);
  if (lane==0) atomicAdd(&gpos[g*(AN*3)+ac], s);
}

__global__ void k_force(const float* __restrict__ gpos, float* __restrict__ ob)
{
  int i=blockIdx.x*256+threadIdx.x; if(i>=NN*3) return;
  ob[GN+i]=-gpos[i];
}

extern "C" void kernel_launch(void* const* d_in, const int* in_sizes, int n_in,
                              void* d_out, int out_size, void* d_ws, size_t ws_size,
                              hipStream_t stream)
{
  const int*   x      = (const int*)d_in[0];
  const int*   ei     = (const int*)d_in[1];
  const int*   neo    = (const int*)d_in[2];
  const int*   ai     = (const int*)d_in[3];
  const int*   aj     = (const int*)d_in[4];
  const int*   ak     = (const int*)d_in[5];
  const int*   eb     = (const int*)d_in[6];
  const float* pos    = (const float*)d_in[8];
  const float* eattr  = (const float*)d_in[9];
  const float* eagrad = (const float*)d_in[10];
  const float* etab   = (const float*)d_in[11];
  const float* matW   = (const float*)d_in[12];
  const float* matB   = (const float*)d_in[13];
  const float* rbfW   = (const float*)d_in[14];
  const float* rbfB   = (const float*)d_in[15];
  const float* embtW  = (const float*)d_in[16];
  const float* embtB  = (const float*)d_in[17];
  const float* inW    = (const float*)d_in[18];
  const float* inB    = (const float*)d_in[19];
  const float* Wq     = (const float*)d_in[20];
  const float* Wk     = (const float*)d_in[21];
  const float* Wv     = (const float*)d_in[22];
  const float* Wo     = (const float*)d_in[23];
  const float* bo     = (const float*)d_in[24];
  const float* Wsbf   = (const float*)d_in[25];
  const float* Weat   = (const float*)d_in[26];
  const float* o1W    = (const float*)d_in[27];
  const float* o1B    = (const float*)d_in[28];
  const float* o2W    = (const float*)d_in[29];
  const float* o2B    = (const float*)d_in[30];
  float* out = (float*)d_out;
  (void)in_sizes; (void)n_in; (void)out_size; (void)ws_size;

  float* w=(float*)d_ws;
  size_t off=0;
  auto A=[&](size_t n){ float* p=w+off; off+=n; return p; };
  float* dv    = A(EN);
  float* env   = A(EN);
  float* denv  = A(EN);
  float* gd    = A(EN);
  float* nrbf  = A((size_t)EN*RBFD);
  float* gnr   = A((size_t)EN*RBFD);
  float* geaenv= A((size_t)EN*MATD);
  float* eag   = A((size_t)EN*MATD);
  float* p1    = A((size_t)EN*EMBD);
  float* p2    = A((size_t)EN*EMBD);
  float* p3    = A((size_t)EN*EMBD);
  float* g1pre = A((size_t)EN*EMBD);
  float* ghpre = A((size_t)EN*EMBD);
  float* gp1   = A((size_t)EN*EMBD);
  float* gp2   = A((size_t)EN*EMBD);
  float* hlay  = A((size_t)5*EN*CHD);
  float* qkv4  = A((size_t)4*EN*768);
  float* gqkv  = A((size_t)EN*768);
  float* eatn4 = A((size_t)4*NN*CHD);
  float* sc2   = A((size_t)EN*CHD);     // agg fwd / grad_agg bwd
  float* gradh = A((size_t)EN*CHD);
  float* opre4 = A((size_t)4*EN*CHD);
  float* sbf   = A((size_t)TN*SBFW);
  float* gsbf  = A((size_t)TN*SBFW);
  float* angb  = A(TN);
  float* attn4 = A((size_t)4*TN*HEADS);
  float* glog  = A((size_t)TN*HEADS);
  float* esb4  = A((size_t)4*TN*CHD);   // per-layer, stored fwd->bwd
  float* gesb  = A((size_t)TN*CHD);
  float* embx  = A((size_t)NN*EMBD);
  float* gpos  = A((size_t)NN*3);
  // total ~118M floats ~= 471 MB

  #define GX(TRB,SEL,AMOD,EPI, Ap,B0p,B1p,B2p,biasp,Cp,o2p,a0p,a1p,e0p,e1p,hinp, M,Nc,K,acc,sA,sB,sC,batch) \
    hipLaunchKernelGGL((gemmX<TRB,SEL,AMOD,EPI>), dim3(((Nc)+63)/64,((M)+63)/64,(batch)), dim3(256),0,stream, \
      Ap,B0p,B1p,B2p,biasp,Cp,o2p,a0p,a1p,e0p,e1p,hinp, M,Nc,K,acc,(size_t)(sA),(size_t)(sB),(size_t)(sC))

  const float* FN = nullptr; float* FNm = nullptr;

  // ---------- init + geometry ----------
  hipLaunchKernelGGL(k_init, dim3((TN*SBFW+255)/256),dim3(256),0,stream, out,gsbf,gpos);
  hipLaunchKernelGGL(k_edge_geom, dim3((EN+255)/256),dim3(256),0,stream, pos,ei,dv,env,denv,nrbf);
  hipLaunchKernelGGL(k_ang, dim3((TN+255)/256),dim3(256),0,stream, pos,ai,aj,ak,angb);
  hipLaunchKernelGGL(k_sbf, dim3((TN*SBFW+255)/256),dim3(256),0,stream, angb,nrbf,neo,sbf);
  hipLaunchKernelGGL(k_embx, dim3((NN*EMBD+255)/256),dim3(256),0,stream, x,etab,embx);

  // ---------- embedding MLP ----------
  GX(0,0,5,0, eattr,matW,FN,FN, matB, p1, FNm, env,FN, FN,FN,FN, EN,EMBD,MATD,0, 0,0,0, 1);
  GX(0,0,0,0, nrbf, rbfW,FN,FN, rbfB, p2, FNm, FN,FN, FN,FN,FN, EN,EMBD,RBFD,0, 0,0,0, 1);
  GX(0,0,2,0, p1, embtW,FN,FN, embtB, p3, FNm, p1,p2, FN,FN,FN, EN,EMBD,CHD,0, 0,0,0, 1);
  GX(0,0,1,0, p3, inW,FN,FN, inB, hlay, FNm, FN,FN, FN,FN,FN, EN,CHD,EMBD,0, 0,0,0, 1);

  // ---------- batched per-layer precompute ----------
  GX(0,0,0,0, embx, Weat,FN,FN, FN, eatn4, FNm, FN,FN, FN,FN,FN,
     NN,CHD,EMBD,0, 0,(size_t)EMBD*CHD,(size_t)NN*CHD, LN);
  GX(0,0,0,0, sbf, Wsbf,FN,FN, FN, esb4, FNm, FN,FN, FN,FN,FN,
     TN,CHD,SBFW,0, 0,(size_t)SBFW*CHD,(size_t)TN*CHD, LN);

  // ---------- forward layers ----------
  for (int l=0;l<LN;l++){
    float* hl   = hlay+(size_t)l*EN*CHD;
    float* qkvl = qkv4+(size_t)l*EN*768;
    float* esbl = esb4+(size_t)l*TN*CHD;
    float* eatl = eatn4+(size_t)l*NN*CHD;
    float* attl = attn4+(size_t)l*TN*HEADS;
    float* opl  = opre4+(size_t)l*EN*CHD;
    GX(0,1,0,0, hl, Wq+(size_t)l*CHD*CHD, Wk+(size_t)l*CHD*CHD, Wv+(size_t)l*CHD*CHD,
       FN, qkvl, FNm, FN,FN, FN,FN,FN, EN,768,CHD,0, 0,0,0, 1);
    hipLaunchKernelGGL(k_attn_fwd, dim3((EN*HEADS+255)/256),dim3(256),0,stream,
                       qkvl,esbl,eatl,neo,attl,sc2);
    GX(0,0,0,1, sc2, Wo+(size_t)l*CHD*CHD,FN,FN, bo+(size_t)l*CHD, opl,
       hlay+(size_t)(l+1)*EN*CHD, FN,FN, FN,FN, hl, EN,CHD,CHD,0, 0,0,0, 1);
  }
  const float* h4=hlay+(size_t)4*EN*CHD;
  GX(0,0,0,0, h4, o1W,FN,FN, o1B, g1pre, FNm, FN,FN, FN,FN,FN, EN,EMBD,CHD,0, 0,0,0, 1);
  hipLaunchKernelGGL(k_edge_out, dim3((EN+255)/256),dim3(256),0,stream, g1pre,o2W,o2B,eb,out);

  // ---------- backward ----------
  GX(1,0,4,0, g1pre, o1W,FN,FN, FN, gradh, FNm, o2W,FN, FN,FN,FN, EN,CHD,EMBD,0, 0,0,0, 1);

  for (int l=LN-1;l>=0;l--){
    float* qkvl = qkv4+(size_t)l*EN*768;
    float* esbl = esb4+(size_t)l*TN*CHD;
    float* eatl = eatn4+(size_t)l*NN*CHD;
    float* attl = attn4+(size_t)l*TN*HEADS;
    float* opl  = opre4+(size_t)l*EN*CHD;
    GX(1,0,3,0, gradh, Wo+(size_t)l*CHD*CHD,FN,FN, FN, sc2, FNm, opl,FN, FN,FN,FN,
       EN,CHD,CHD,0, 0,0,0, 1);   // grad_agg
    hipLaunchKernelGGL(k_attn_bwd_edge, dim3((EN*HEADS+255)/256),dim3(256),0,stream,
                       qkvl,esbl,eatl,attl,sc2,neo,gqkv,gesb,glog);
    hipLaunchKernelGGL(k_attn_bwd_src, dim3((EN*HEADS+255)/256),dim3(256),0,stream,
                       qkvl,esbl,attl,sc2,glog,gqkv);
    GX(1,0,0,0, gesb, Wsbf+(size_t)l*SBFW*CHD,FN,FN, FN, gsbf, FNm, FN,FN, FN,FN,FN,
       TN,SBFW,CHD,1, 0,0,0, 1);
    GX(0,2,0,0, gqkv, Wq+(size_t)l*CHD*CHD, Wk+(size_t)l*CHD*CHD, Wv+(size_t)l*CHD*CHD,
       FN, gradh, FNm, FN,FN, FN,FN,FN, EN,CHD,768,1, 0,0,0, 1);
  }

  GX(1,0,0,2, gradh, inW,FN,FN, FN, ghpre, FNm, FN,FN, p3,FN,FN, EN,EMBD,CHD,0, 0,0,0, 1);
  GX(1,0,0,3, ghpre, embtW,FN,FN, FN, gp1, gp2, FN,FN, p1,p2,FN, EN,CHD,EMBD,0, 0,0,0, 1);
  GX(1,0,0,0, gp2, rbfW,FN,FN, FN, gnr, FNm, FN,FN, FN,FN,FN, EN,RBFD,EMBD,0, 0,0,0, 1);
  GX(1,0,0,0, gp1, matW,FN,FN, FN, geaenv, FNm, FN,FN, FN,FN,FN, EN,MATD,EMBD,0, 0,0,0, 1);
  hipLaunchKernelGGL(k_edge_bwd, dim3((EN+255)/256),dim3(256),0,stream,
                     geaenv,eattr,env,denv,dv,gnr,eag,gd);
  hipLaunchKernelGGL(k_sbf_bwd, dim3((TN+255)/256),dim3(256),0,stream,
                     gsbf,angb,dv,env,denv,nrbf,neo,ai,aj,ak,pos,gd,gpos);
  hipLaunchKernelGGL(k_d_bwd, dim3((EN+255)/256),dim3(256),0,stream, gd,dv,pos,ei,gpos);
  hipLaunchKernelGGL(k_einsum2, dim3(2304),dim3(256),0,stream, eagrad,eag,gpos);
  hipLaunchKernelGGL(k_force, dim3((NN*3+255)/256),dim3(256),0,stream, gpos,out);
  #undef GX
}